// Round 4
// baseline (434.674 us; speedup 1.0000x reference)
//
#include <hip/hip_runtime.h>
#include <stdint.h>

// Problem constants
constexpr int SEQ   = 2048;
constexpr int NHEAD = 16;
constexpr int HDSZ  = 128;   // head dim
constexpr int HDIM  = 2048;  // model dim
constexpr float QK_SCALE = 0.08838834764831845f; // 1/sqrt(128)

typedef __attribute__((ext_vector_type(8))) __bf16 bf16x8;
typedef __attribute__((ext_vector_type(4))) __bf16 bf16x4;
typedef __attribute__((ext_vector_type(4))) float  f32x4;

__device__ __forceinline__ void gl_lds16(const void* gptr, void* lptr) {
  // async global->LDS, 16B/lane; LDS dst is wave-uniform base + lane*16
  __builtin_amdgcn_global_load_lds(
      (const __attribute__((address_space(1))) unsigned int*)gptr,
      (__attribute__((address_space(3))) unsigned int*)lptr, 16, 0, 0);
}

// ---------------- fp32 -> bf16 casts ----------------
__global__ __launch_bounds__(256) void cast_f32_bf16(
    const float* __restrict__ in, __bf16* __restrict__ out, int n4) {
  int i = blockIdx.x * blockDim.x + threadIdx.x;
  int stride = gridDim.x * blockDim.x;
  for (; i < n4; i += stride) {
    float4 v = ((const float4*)in)[i];
    bf16x4 o = { (__bf16)v.x, (__bf16)v.y, (__bf16)v.z, (__bf16)v.w };
    ((bf16x4*)out)[i] = o;
  }
}

// 4 weight matrices in one launch; dsts are contiguous at out + y*WN
__global__ __launch_bounds__(256) void cast4_f32_bf16(
    const float* __restrict__ w0, const float* __restrict__ w1,
    const float* __restrict__ w2, const float* __restrict__ w3,
    __bf16* __restrict__ out, int n4) {
  const int y = blockIdx.y;
  const float* src = (y == 0) ? w0 : (y == 1) ? w1 : (y == 2) ? w2 : w3;
  __bf16* dst = out + (size_t)y * (size_t)n4 * 4;
  int i = blockIdx.x * blockDim.x + threadIdx.x;
  int stride = gridDim.x * blockDim.x;
  for (; i < n4; i += stride) {
    float4 v = ((const float4*)src)[i];
    bf16x4 o = { (__bf16)v.x, (__bf16)v.y, (__bf16)v.z, (__bf16)v.w };
    ((bf16x4*)dst)[i] = o;
  }
}

// ---------------- NT GEMM: C[M,N] = A[M,K] * B[N,K]^T ----------------
// m97 structure: 128x128 tile, BK=32, 4 waves, global_load_lds(16B) staging.
// Grid is FIXED dim3(16,32) = 512 blocks; XCD-aware swizzle (512%8==0).
// MODE 0: bf16 out scattered to [b, h, s, d] (Q,K).
// MODE 1: fp32 row-major (final output).
// MODE 2: bf16 out TRANSPOSED to [b, h, d, s] (V) via LDS tile transpose.
template <int MODE>
__global__ __launch_bounds__(256) void gemm_bt(
    const __bf16* __restrict__ A, const __bf16* __restrict__ B,
    void* __restrict__ C, int M, int N, int K) {
  __shared__ __bf16 As[128 * 32];
  __shared__ __bf16 Bs[128 * 32];
  const int tid  = threadIdx.x;
  const int lane = tid & 63;
  const int w    = tid >> 6;
  const int lg   = lane >> 4, lr = lane & 15;
  const int wr   = w >> 1, wc = w & 1;
  // T1 XCD swizzle: 512 blocks -> 8 chunks of 64 (one per XCD)
  const int flat = blockIdx.y * 16 + blockIdx.x;
  const int swz  = (flat & 7) * 64 + (flat >> 3);
  const long mbase = (long)(swz >> 4) * 128;
  const long nbase = (long)(swz & 15) * 128;

  f32x4 acc[4][4];
#pragma unroll
  for (int i = 0; i < 4; ++i)
#pragma unroll
    for (int j = 0; j < 4; ++j) acc[i][j] = (f32x4){0.f, 0.f, 0.f, 0.f};

  const int srow = lane >> 2;       // row within 16-row staging chunk
  const int scol = (lane & 3) * 8;  // bf16 elem offset (16B granules)

  for (int kt = 0; kt < K; kt += 32) {
#pragma unroll
    for (int i = 0; i < 2; ++i) {
      const int c = w * 2 + i;  // 8 chunks of 16 rows x 32 k each
      gl_lds16(A + (mbase + c * 16 + srow) * (long)K + kt + scol, &As[c * 512]);
      gl_lds16(B + (nbase + c * 16 + srow) * (long)K + kt + scol, &Bs[c * 512]);
    }
    __syncthreads();
    bf16x8 af[4], bfv[4];
#pragma unroll
    for (int mm = 0; mm < 4; ++mm)
      af[mm] = *(const bf16x8*)&As[(wr * 64 + mm * 16 + lr) * 32 + lg * 8];
#pragma unroll
    for (int nn = 0; nn < 4; ++nn)
      bfv[nn] = *(const bf16x8*)&Bs[(wc * 64 + nn * 16 + lr) * 32 + lg * 8];
    __builtin_amdgcn_s_setprio(1);
#pragma unroll
    for (int nn = 0; nn < 4; ++nn)
#pragma unroll
      for (int mm = 0; mm < 4; ++mm)
        acc[mm][nn] = __builtin_amdgcn_mfma_f32_16x16x32_bf16(
            af[mm], bfv[nn], acc[mm][nn], 0, 0, 0);
    __builtin_amdgcn_s_setprio(0);
    __syncthreads();
  }

  // Epilogue. D layout (m89-verified): col = lane&15, row = (lane>>4)*4 + r
  if constexpr (MODE == 2) {
    // transpose 128x128 tile through LDS, write [b, h, d, s] coalesced
    __shared__ __bf16 Ts[128 * 136];
#pragma unroll
    for (int mm = 0; mm < 4; ++mm)
#pragma unroll
      for (int nn = 0; nn < 4; ++nn) {
        const int d = wc * 64 + nn * 16 + lr;
#pragma unroll
        for (int r = 0; r < 4; ++r) {
          const int sl = wr * 64 + mm * 16 + lg * 4 + r;
          Ts[d * 136 + sl] = (__bf16)acc[mm][nn][r];
        }
      }
    __syncthreads();
    const long b  = mbase >> 11;
    const long s0 = mbase & 2047;
    const long h  = nbase >> 7;
    __bf16* out = (__bf16*)C;
#pragma unroll
    for (int it = 0; it < 8; ++it) {
      const int idx = it * 256 + tid;
      const int d = idx >> 4, c = idx & 15;
      bf16x8 v = *(const bf16x8*)&Ts[d * 136 + c * 8];
      *(bf16x8*)&out[((b * NHEAD + h) * HDSZ + d) * SEQ + s0 + c * 8] = v;
    }
  } else {
#pragma unroll
    for (int mm = 0; mm < 4; ++mm) {
#pragma unroll
      for (int nn = 0; nn < 4; ++nn) {
        const long n = nbase + wc * 64 + nn * 16 + lr;
#pragma unroll
        for (int r = 0; r < 4; ++r) {
          const long m = mbase + wr * 64 + mm * 16 + lg * 4 + r;
          if (MODE == 0) {
            const long b = m >> 11, s = m & 2047;
            const long h = n >> 7,  d = n & 127;
            ((__bf16*)C)[((b * NHEAD + h) * SEQ + s) * HDSZ + d] =
                (__bf16)acc[mm][nn][r];
          } else {
            ((float*)C)[m * (long)N + n] = acc[mm][nn][r];
          }
        }
      }
    }
  }
}

// ---------------- fused flash attention v4 ----------------
// QBLK=64 (wave owns 16 q-rows), KVBLK=32, grid 1024 blocks = 4/CU.
// LDS 36KB: Ks dbuf 16K + Vs dbuf 16K + Ps 4K  -> occupancy 4 blocks/CU.
// K/V double-buffered via global_load_lds with pre-swizzled global source;
// STAGE(t+1) issued after mask loads, drained at end-of-iteration barrier.
__global__ __launch_bounds__(256, 4) void attn_fused(
    const __bf16* __restrict__ Q, const __bf16* __restrict__ K,
    const __bf16* __restrict__ Vt, const float* __restrict__ mask,
    __bf16* __restrict__ Out) {
  __shared__ __bf16 Ks[2 * 32 * 128];   // [buf][krow][d], swizzled chunks
  __shared__ __bf16 Vs[2 * 128 * 32];   // [buf][d][kcol], swizzled chunks
  __shared__ __bf16 Ps[64 * 32];        // [qrow][kcol], swizzled chunks

  const int tid  = threadIdx.x;
  const int lane = tid & 63;
  const int w    = tid >> 6;
  const int lg   = lane >> 4, lr = lane & 15;
  // XCD swizzle over 1024 blocks: 8 chunks of 128 (4 heads per XCD)
  const int flat = blockIdx.y * 32 + blockIdx.x;
  const int swz  = (flat & 7) * 128 + (flat >> 3);
  const int bh   = swz >> 5;          // b*NHEAD + h
  const int b    = bh >> 4, h = bh & 15;
  const int q0   = (swz & 31) * 64;

  const __bf16* Qh = Q  + (size_t)bh * SEQ * HDSZ;
  const __bf16* Kh = K  + (size_t)bh * SEQ * HDSZ;
  const __bf16* Vh = Vt + (size_t)bh * HDSZ * SEQ;  // [d][s]
  const float*  Mb = mask + (size_t)b * SEQ * SEQ;

  // Q fragments: wave rows q0 + w*16 + lr (A-operand: row=lr, k=lg*8+i)
  bf16x8 qf[4];
#pragma unroll
  for (int kk = 0; kk < 4; ++kk)
    qf[kk] = *(const bf16x8*)(
        Qh + (size_t)(q0 + w * 16 + lr) * HDSZ + kk * 32 + lg * 8);

  // staging source pointers (pre-swizzled global addresses, linear LDS dest)
  // K tile [32][128]: 512 chunks of 16B, row = 16 chunks, swz: c ^= row&7
  // V tile [128][32]: 512 chunks of 16B, row = 4 chunks,  swz: c ^= row&3
  const __bf16* ksrc[2];
  const __bf16* vsrc[2];
#pragma unroll
  for (int i = 0; i < 2; ++i) {
    const int kch = i * 256 + tid;
    const int krow = kch >> 4, kc = kch & 15;
    ksrc[i] = Kh + (size_t)krow * HDSZ + ((kc ^ (krow & 7)) * 8);
    const int vch = i * 256 + tid;
    const int vrow = vch >> 2, vc = vch & 3;
    vsrc[i] = Vh + (size_t)vrow * SEQ + ((vc ^ (vrow & 3)) * 8);
  }

  float mrw[4], lrw[4];
#pragma unroll
  for (int r = 0; r < 4; ++r) { mrw[r] = -1e30f; lrw[r] = 0.f; }
  f32x4 acco[8];
#pragma unroll
  for (int n = 0; n < 8; ++n) acco[n] = (f32x4){0.f, 0.f, 0.f, 0.f};

  // prologue: stage tile 0 into buffer 0
#pragma unroll
  for (int i = 0; i < 2; ++i) {
    gl_lds16(ksrc[i], &Ks[(i * 256 + w * 64) * 8]);
    gl_lds16(vsrc[i], &Vs[(i * 256 + w * 64) * 8]);
  }
  __syncthreads();

  constexpr int NT = SEQ / 32;
  for (int t = 0; t < NT; ++t) {
    const int cur = t & 1;
    const int kt = t * 32;
    const char* Kb = (const char*)(Ks + cur * (32 * 128));
    const char* Vb = (const char*)(Vs + cur * (128 * 32));

    // --- (A) mask prefetch to regs FIRST (oldest vmem -> softmax's wait
    //     keeps the stage below in flight) ---
    float mk[2][4];
#pragma unroll
    for (int r = 0; r < 4; ++r) {
      const float* mp =
          Mb + (size_t)(q0 + w * 16 + lg * 4 + r) * SEQ + kt + lr;
      mk[0][r] = mp[0];
      mk[1][r] = mp[16];
    }
    __builtin_amdgcn_sched_barrier(0);

    // --- (B) STAGE tile t+1 into buf^1 (drained only at end barrier) ---
    if (t + 1 < NT) {
      const int nk = kt + 32;
      __bf16* Kn = Ks + (cur ^ 1) * (32 * 128);
      __bf16* Vn = Vs + (cur ^ 1) * (128 * 32);
#pragma unroll
      for (int i = 0; i < 2; ++i) {
        gl_lds16(ksrc[i] + (size_t)nk * HDSZ, &Kn[(i * 256 + w * 64) * 8]);
        gl_lds16(vsrc[i] + nk, &Vn[(i * 256 + w * 64) * 8]);
      }
    }
    __builtin_amdgcn_sched_barrier(0);

    // --- (C) S = Q K^T (per wave: 16 rows x 32 cols) ---
    f32x4 sacc[2];
#pragma unroll
    for (int n = 0; n < 2; ++n) sacc[n] = (f32x4){0.f, 0.f, 0.f, 0.f};
    __builtin_amdgcn_s_setprio(1);
#pragma unroll
    for (int n = 0; n < 2; ++n)
#pragma unroll
      for (int kk = 0; kk < 4; ++kk) {
        const int cp = (kk * 4 + lg) ^ (lr & 7);  // swizzled 16B chunk
        bf16x8 kf = *(const bf16x8*)(Kb + ((n * 16 + lr) << 8) + (cp << 4));
        sacc[n] = __builtin_amdgcn_mfma_f32_16x16x32_bf16(qf[kk], kf, sacc[n], 0, 0, 0);
      }
    __builtin_amdgcn_s_setprio(0);

    // --- (D) online softmax (rows = w*16 + lg*4 + r, cols = n*16 + lr) ---
    float sv[2][4], tmax[4];
#pragma unroll
    for (int r = 0; r < 4; ++r) {
      sv[0][r] = fmaf(sacc[0][r], QK_SCALE, mk[0][r]);
      sv[1][r] = fmaf(sacc[1][r], QK_SCALE, mk[1][r]);
      tmax[r]  = fmaxf(sv[0][r], sv[1][r]);
    }
#pragma unroll
    for (int r = 0; r < 4; ++r)
#pragma unroll
      for (int off = 1; off < 16; off <<= 1)
        tmax[r] = fmaxf(tmax[r], __shfl_xor(tmax[r], off));
    float corr[4];
#pragma unroll
    for (int r = 0; r < 4; ++r) {
      float mn = fmaxf(mrw[r], tmax[r]);
      corr[r] = __expf(mrw[r] - mn);
      mrw[r] = mn;
    }
    float lsum[4];
#pragma unroll
    for (int r = 0; r < 4; ++r) {
      float p0 = __expf(sv[0][r] - mrw[r]);
      float p1 = __expf(sv[1][r] - mrw[r]);
      sv[0][r] = p0; sv[1][r] = p1;
      lsum[r] = p0 + p1;
    }
#pragma unroll
    for (int r = 0; r < 4; ++r) {
#pragma unroll
      for (int off = 1; off < 16; off <<= 1) lsum[r] += __shfl_xor(lsum[r], off);
      lrw[r] = lrw[r] * corr[r] + lsum[r];
    }
#pragma unroll
    for (int n = 0; n < 8; ++n)
#pragma unroll
      for (int r = 0; r < 4; ++r) acco[n][r] *= corr[r];

    // --- (E) P tile (bf16) -> swizzled LDS; wave-local rows, no barrier ---
    // row = w*16 + lg*4 + r (g = (row>>2)&3 = lg); chunk ^= g
#pragma unroll
    for (int n = 0; n < 2; ++n)
#pragma unroll
      for (int r = 0; r < 4; ++r) {
        const int prow  = w * 16 + lg * 4 + r;
        const int pbyte = (n * 32 + lr * 2) ^ (lg << 4);
        *(__bf16*)((char*)Ps + prow * 64 + pbyte) = (__bf16)sv[n][r];
      }
    __asm__ volatile("s_waitcnt lgkmcnt(0)" ::: "memory");
    __builtin_amdgcn_sched_barrier(0);

    // --- (F) O += P V ---
    __builtin_amdgcn_s_setprio(1);
    {
      const int pg = (lr >> 2) & 3;  // reader row = w*16+lr -> g
      bf16x8 pa = *(const bf16x8*)(
          (const char*)Ps + (w * 16 + lr) * 64 + ((lg ^ pg) << 4));
#pragma unroll
      for (int n = 0; n < 8; ++n) {
        const int cp = lg ^ (lr & 3);
        bf16x8 vf = *(const bf16x8*)(Vb + ((n * 16 + lr) << 6) + (cp << 4));
        acco[n] = __builtin_amdgcn_mfma_f32_16x16x32_bf16(pa, vf, acco[n], 0, 0, 0);
      }
    }
    __builtin_amdgcn_s_setprio(0);

    // --- (G) publish next buffer / protect current from overwrite ---
    __syncthreads();
  }

  // --- epilogue: normalize, write attn out as [b, s, h*128+d] bf16 ---
#pragma unroll
  for (int r = 0; r < 4; ++r) {
    const float inv = 1.0f / lrw[r];
    const int srow = q0 + w * 16 + lg * 4 + r;
    const size_t base = ((size_t)b * SEQ + srow) * HDIM + h * HDSZ;
#pragma unroll
    for (int n = 0; n < 8; ++n)
      Out[base + n * 16 + lr] = (__bf16)(acco[n][r] * inv);
  }
}

// ---------------- launcher ----------------
extern "C" void kernel_launch(void* const* d_in, const int* in_sizes, int n_in,
                              void* d_out, int out_size, void* d_ws, size_t ws_size,
                              hipStream_t stream) {
  const float* x    = (const float*)d_in[0];
  const float* mask = (const float*)d_in[1];
  const float* wq   = (const float*)d_in[2];
  const float* wk   = (const float*)d_in[3];
  const float* wv   = (const float*)d_in[4];
  const float* wo   = (const float*)d_in[5];

  constexpr long XN = 4096L * 2048;  // 8388608
  constexpr long WN = 2048L * 2048;  // 4194304

  __bf16* xbf = (__bf16*)d_ws;
  __bf16* wqb = xbf + XN;
  __bf16* wkb = wqb + WN;
  __bf16* wvb = wkb + WN;
  __bf16* wob = wvb + WN;
  __bf16* qw  = wob + WN;
  __bf16* kw  = qw + XN;
  __bf16* vtw = kw + XN;             // V pre-transposed: [b, h, d, s]
  __bf16* aw  = vtw + XN;            // attention output [4096][2048]

  cast_f32_bf16<<<2048, 256, 0, stream>>>(x, xbf, (int)(XN / 4));
  cast4_f32_bf16<<<dim3(256, 4), 256, 0, stream>>>(wq, wk, wv, wo, wqb,
                                                   (int)(WN / 4));

  dim3 gg(16, 32);  // (N-tiles, M-tiles) — FIXED, kernel swizzles internally
  gemm_bt<0><<<gg, 256, 0, stream>>>(xbf, wqb, qw,  4096, 2048, 2048);
  gemm_bt<0><<<gg, 256, 0, stream>>>(xbf, wkb, kw,  4096, 2048, 2048);
  gemm_bt<2><<<gg, 256, 0, stream>>>(xbf, wvb, vtw, 4096, 2048, 2048);

  attn_fused<<<dim3(32, 32), 256, 0, stream>>>(qw, kw, vtw, mask, aw);

  gemm_bt<1><<<gg, 256, 0, stream>>>(aw, wob, d_out, 4096, 2048, 2048);
}

// Round 5
// 363.511 us; speedup vs baseline: 1.1958x; 1.1958x over previous
//
#include <hip/hip_runtime.h>
#include <stdint.h>

// Problem constants
constexpr int SEQ   = 2048;
constexpr int NHEAD = 16;
constexpr int HDSZ  = 128;   // head dim
constexpr int HDIM  = 2048;  // model dim
constexpr float QK_SCALE = 0.08838834764831845f; // 1/sqrt(128)

typedef __attribute__((ext_vector_type(8))) __bf16 bf16x8;
typedef __attribute__((ext_vector_type(4))) __bf16 bf16x4;
typedef __attribute__((ext_vector_type(4))) float  f32x4;

__device__ __forceinline__ void gl_lds16(const void* gptr, void* lptr) {
  // async global->LDS, 16B/lane; LDS dst is wave-uniform base + lane*16
  __builtin_amdgcn_global_load_lds(
      (const __attribute__((address_space(1))) unsigned int*)gptr,
      (__attribute__((address_space(3))) unsigned int*)lptr, 16, 0, 0);
}

// ---------------- fp32 -> bf16 casts ----------------
__global__ __launch_bounds__(256) void cast_f32_bf16(
    const float* __restrict__ in, __bf16* __restrict__ out, int n4) {
  int i = blockIdx.x * blockDim.x + threadIdx.x;
  int stride = gridDim.x * blockDim.x;
  for (; i < n4; i += stride) {
    float4 v = ((const float4*)in)[i];
    bf16x4 o = { (__bf16)v.x, (__bf16)v.y, (__bf16)v.z, (__bf16)v.w };
    ((bf16x4*)out)[i] = o;
  }
}

// 4 weight matrices in one launch; dsts are contiguous at out + y*WN
__global__ __launch_bounds__(256) void cast4_f32_bf16(
    const float* __restrict__ w0, const float* __restrict__ w1,
    const float* __restrict__ w2, const float* __restrict__ w3,
    __bf16* __restrict__ out, int n4) {
  const int y = blockIdx.y;
  const float* src = (y == 0) ? w0 : (y == 1) ? w1 : (y == 2) ? w2 : w3;
  __bf16* dst = out + (size_t)y * (size_t)n4 * 4;
  int i = blockIdx.x * blockDim.x + threadIdx.x;
  int stride = gridDim.x * blockDim.x;
  for (; i < n4; i += stride) {
    float4 v = ((const float4*)src)[i];
    bf16x4 o = { (__bf16)v.x, (__bf16)v.y, (__bf16)v.z, (__bf16)v.w };
    ((bf16x4*)dst)[i] = o;
  }
}

// ---------------- merged QKV GEMM ----------------
// C = A[4096,2048] * W[6144,2048]^T ; W = [wq; wk; wv] contiguous.
// n-tile 0..15 -> Q scatter [b,h,s,d]; 16..31 -> K scatter; 32..47 -> V
// transposed to [b,h,d,s] via half-tile LDS transpose.
// grid FIXED dim3(48,32) = 1536 blocks, XCD swizzle (1536%8==0).
__global__ __launch_bounds__(256) void gemm_qkv(
    const __bf16* __restrict__ A, const __bf16* __restrict__ W,
    __bf16* __restrict__ qkv) {
  constexpr long XN = 4096L * 2048;
  constexpr int K = 2048;
  __shared__ __bf16 As[128 * 32];
  __shared__ __bf16 Bs[128 * 32];
  __shared__ __bf16 Ts[64 * 136];  // V transpose half-tile
  const int tid  = threadIdx.x;
  const int lane = tid & 63;
  const int w    = tid >> 6;
  const int lg   = lane >> 4, lr = lane & 15;
  const int wr   = w >> 1, wc = w & 1;
  const int flat = blockIdx.y * 48 + blockIdx.x;
  const int swz  = (flat & 7) * 192 + (flat >> 3);
  const int mtile = swz & 31, ntile = swz >> 5;  // 0..31, 0..47
  const long mbase = (long)mtile * 128;
  const long nbase = (long)ntile * 128;

  f32x4 acc[4][4];
#pragma unroll
  for (int i = 0; i < 4; ++i)
#pragma unroll
    for (int j = 0; j < 4; ++j) acc[i][j] = (f32x4){0.f, 0.f, 0.f, 0.f};

  const int srow = lane >> 2;
  const int scol = (lane & 3) * 8;

  for (int kt = 0; kt < K; kt += 32) {
#pragma unroll
    for (int i = 0; i < 2; ++i) {
      const int c = w * 2 + i;
      gl_lds16(A + (mbase + c * 16 + srow) * (long)K + kt + scol, &As[c * 512]);
      gl_lds16(W + (nbase + c * 16 + srow) * (long)K + kt + scol, &Bs[c * 512]);
    }
    __syncthreads();
    bf16x8 af[4], bfv[4];
#pragma unroll
    for (int mm = 0; mm < 4; ++mm)
      af[mm] = *(const bf16x8*)&As[(wr * 64 + mm * 16 + lr) * 32 + lg * 8];
#pragma unroll
    for (int nn = 0; nn < 4; ++nn)
      bfv[nn] = *(const bf16x8*)&Bs[(wc * 64 + nn * 16 + lr) * 32 + lg * 8];
    __builtin_amdgcn_s_setprio(1);
#pragma unroll
    for (int nn = 0; nn < 4; ++nn)
#pragma unroll
      for (int mm = 0; mm < 4; ++mm)
        acc[mm][nn] = __builtin_amdgcn_mfma_f32_16x16x32_bf16(
            af[mm], bfv[nn], acc[mm][nn], 0, 0, 0);
    __builtin_amdgcn_s_setprio(0);
    __syncthreads();
  }

  const int  mat = ntile >> 4;              // 0=Q, 1=K, 2=V
  const long nb2 = nbase - (long)mat * 2048;  // col within matrix
  const long b   = mbase >> 11, s0 = mbase & 2047;
  const long h   = nb2 >> 7;
  if (mat < 2) {
    __bf16* out = qkv + (size_t)mat * XN;
#pragma unroll
    for (int mm = 0; mm < 4; ++mm)
#pragma unroll
      for (int nn = 0; nn < 4; ++nn) {
        const long n = nb2 + wc * 64 + nn * 16 + lr;
        const long d = n & 127, hh = n >> 7;
#pragma unroll
        for (int r = 0; r < 4; ++r) {
          const long m = mbase + wr * 64 + mm * 16 + lg * 4 + r;
          out[(((m >> 11) * NHEAD + hh) * SEQ + (m & 2047)) * HDSZ + d] =
              (__bf16)acc[mm][nn][r];
        }
      }
  } else {
    // V: transpose tile to [b, h, d, s] in two 64-row halves
    __bf16* out = qkv + 2 * XN;
#pragma unroll
    for (int dh = 0; dh < 2; ++dh) {
      if (wc == dh) {
#pragma unroll
        for (int mm = 0; mm < 4; ++mm)
#pragma unroll
          for (int nn = 0; nn < 4; ++nn) {
            const int dd = nn * 16 + lr;  // 0..63 within half
#pragma unroll
            for (int r = 0; r < 4; ++r)
              Ts[dd * 136 + wr * 64 + mm * 16 + lg * 4 + r] =
                  (__bf16)acc[mm][nn][r];
          }
      }
      __syncthreads();
#pragma unroll
      for (int it = 0; it < 4; ++it) {
        const int idx = it * 256 + tid;
        const int dd = idx >> 4, c = idx & 15;
        bf16x8 v = *(const bf16x8*)&Ts[dd * 136 + c * 8];
        *(bf16x8*)&out[((b * NHEAD + h) * HDSZ + dh * 64 + dd) * SEQ +
                       s0 + c * 8] = v;
      }
      __syncthreads();
    }
  }
}

// ---------------- plain NT GEMM (fp32 out) for O projection ----------------
__global__ __launch_bounds__(256) void gemm_bt_f32(
    const __bf16* __restrict__ A, const __bf16* __restrict__ B,
    float* __restrict__ C, int M, int N, int K) {
  __shared__ __bf16 As[128 * 32];
  __shared__ __bf16 Bs[128 * 32];
  const int tid  = threadIdx.x;
  const int lane = tid & 63;
  const int w    = tid >> 6;
  const int lg   = lane >> 4, lr = lane & 15;
  const int wr   = w >> 1, wc = w & 1;
  const int flat = blockIdx.y * 16 + blockIdx.x;
  const int swz  = (flat & 7) * 64 + (flat >> 3);
  const long mbase = (long)(swz >> 4) * 128;
  const long nbase = (long)(swz & 15) * 128;

  f32x4 acc[4][4];
#pragma unroll
  for (int i = 0; i < 4; ++i)
#pragma unroll
    for (int j = 0; j < 4; ++j) acc[i][j] = (f32x4){0.f, 0.f, 0.f, 0.f};

  const int srow = lane >> 2;
  const int scol = (lane & 3) * 8;

  for (int kt = 0; kt < K; kt += 32) {
#pragma unroll
    for (int i = 0; i < 2; ++i) {
      const int c = w * 2 + i;
      gl_lds16(A + (mbase + c * 16 + srow) * (long)K + kt + scol, &As[c * 512]);
      gl_lds16(B + (nbase + c * 16 + srow) * (long)K + kt + scol, &Bs[c * 512]);
    }
    __syncthreads();
    bf16x8 af[4], bfv[4];
#pragma unroll
    for (int mm = 0; mm < 4; ++mm)
      af[mm] = *(const bf16x8*)&As[(wr * 64 + mm * 16 + lr) * 32 + lg * 8];
#pragma unroll
    for (int nn = 0; nn < 4; ++nn)
      bfv[nn] = *(const bf16x8*)&Bs[(wc * 64 + nn * 16 + lr) * 32 + lg * 8];
    __builtin_amdgcn_s_setprio(1);
#pragma unroll
    for (int nn = 0; nn < 4; ++nn)
#pragma unroll
      for (int mm = 0; mm < 4; ++mm)
        acc[mm][nn] = __builtin_amdgcn_mfma_f32_16x16x32_bf16(
            af[mm], bfv[nn], acc[mm][nn], 0, 0, 0);
    __builtin_amdgcn_s_setprio(0);
    __syncthreads();
  }

#pragma unroll
  for (int mm = 0; mm < 4; ++mm)
#pragma unroll
    for (int nn = 0; nn < 4; ++nn) {
      const long n = nbase + wc * 64 + nn * 16 + lr;
#pragma unroll
      for (int r = 0; r < 4; ++r) {
        const long m = mbase + wr * 64 + mm * 16 + lg * 4 + r;
        C[m * (long)N + n] = acc[mm][nn][r];
      }
    }
}

// ---------------- fused flash attention v5 ----------------
// QBLK=128, KVBLK=64, **8 waves** (512 threads); wave owns 16 q-rows.
// Same tile/LDS/grid as R3 (80KB, 512 blocks, 2 blocks/CU) but 16 waves/CU.
// K/V double-buffered via global_load_lds with pre-swizzled source; STAGE(t+1)
// issued after mask loads, drained at end-of-iteration barrier.
__global__ __launch_bounds__(512, 4) void attn_fused(
    const __bf16* __restrict__ Q, const __bf16* __restrict__ K,
    const __bf16* __restrict__ Vt, const float* __restrict__ mask,
    __bf16* __restrict__ Out) {
  __shared__ __bf16 Ks[2 * 64 * 128];   // [buf][krow][d], swizzled chunks
  __shared__ __bf16 Vs[2 * 128 * 64];   // [buf][d][kcol], swizzled chunks
  __shared__ __bf16 Ps[128 * 64];       // [qrow][kcol], swizzled chunks

  const int tid  = threadIdx.x;
  const int lane = tid & 63;
  const int w    = tid >> 6;            // 0..7
  const int lg   = lane >> 4, lr = lane & 15;
  const int flat = blockIdx.y * 16 + blockIdx.x;
  const int swz  = (flat & 7) * 64 + (flat >> 3);
  const int bh   = swz >> 4;
  const int b    = bh >> 4, h = bh & 15;
  const int q0   = (swz & 15) * 128;

  const __bf16* Qh = Q  + (size_t)bh * SEQ * HDSZ;
  const __bf16* Kh = K  + (size_t)bh * SEQ * HDSZ;
  const __bf16* Vh = Vt + (size_t)bh * HDSZ * SEQ;  // [d][s]
  const float*  Mb = mask + (size_t)b * SEQ * SEQ;

  // Q fragments: wave rows q0 + w*16 + lr (A-operand: row=lr, k=lg*8+i)
  bf16x8 qf[4];
#pragma unroll
  for (int kk = 0; kk < 4; ++kk)
    qf[kk] = *(const bf16x8*)(
        Qh + (size_t)(q0 + w * 16 + lr) * HDSZ + kk * 32 + lg * 8);

  // staging sources (pre-swizzled global addr, linear LDS dest).
  // K tile [64][128]: 1024 chunks, 16/row, swz c^(row&7).
  // V tile [128][64]: 1024 chunks,  8/row, swz c^(row&7).
  const __bf16* ksrc[2];
  const __bf16* vsrc[2];
#pragma unroll
  for (int i = 0; i < 2; ++i) {
    const int ch = i * 512 + tid;
    const int krow = ch >> 4, kc = ch & 15;
    ksrc[i] = Kh + (size_t)krow * HDSZ + (((kc & 8) | ((kc ^ krow) & 7)) * 8);
    const int vrow = ch >> 3, vc = ch & 7;
    vsrc[i] = Vh + (size_t)vrow * SEQ + (((vc ^ vrow) & 7) * 8);
  }

  float mrw[4], lrw[4];
#pragma unroll
  for (int r = 0; r < 4; ++r) { mrw[r] = -1e30f; lrw[r] = 0.f; }
  f32x4 acco[8];
#pragma unroll
  for (int n = 0; n < 8; ++n) acco[n] = (f32x4){0.f, 0.f, 0.f, 0.f};

  // prologue: stage tile 0 into buffer 0
#pragma unroll
  for (int i = 0; i < 2; ++i) {
    gl_lds16(ksrc[i], &Ks[(i * 512 + w * 64) * 8]);
    gl_lds16(vsrc[i], &Vs[(i * 512 + w * 64) * 8]);
  }
  __syncthreads();

  constexpr int NT = SEQ / 64;
  for (int t = 0; t < NT; ++t) {
    const int cur = t & 1;
    const int kt = t * 64;
    const char* Kb = (const char*)(Ks + cur * (64 * 128));
    const char* Vb = (const char*)(Vs + cur * (128 * 64));

    // --- (A) mask prefetch to regs FIRST (stays oldest vmem) ---
    float mk[4][4];
#pragma unroll
    for (int r = 0; r < 4; ++r) {
      const float* mp =
          Mb + (size_t)(q0 + w * 16 + lg * 4 + r) * SEQ + kt + lr;
#pragma unroll
      for (int n = 0; n < 4; ++n) mk[n][r] = mp[n * 16];
    }
    __builtin_amdgcn_sched_barrier(0);

    // --- (B) STAGE tile t+1 into buf^1 (drained at end barrier) ---
    if (t + 1 < NT) {
      const int nk = kt + 64;
      __bf16* Kn = Ks + (cur ^ 1) * (64 * 128);
      __bf16* Vn = Vs + (cur ^ 1) * (128 * 64);
#pragma unroll
      for (int i = 0; i < 2; ++i) {
        gl_lds16(ksrc[i] + (size_t)nk * HDSZ, &Kn[(i * 512 + w * 64) * 8]);
        gl_lds16(vsrc[i] + nk, &Vn[(i * 512 + w * 64) * 8]);
      }
    }
    __builtin_amdgcn_sched_barrier(0);

    // --- (C) S = Q K^T (per wave: 16 rows x 64 cols) ---
    f32x4 sacc[4];
#pragma unroll
    for (int n = 0; n < 4; ++n) sacc[n] = (f32x4){0.f, 0.f, 0.f, 0.f};
    __builtin_amdgcn_s_setprio(1);
#pragma unroll
    for (int n = 0; n < 4; ++n)
#pragma unroll
      for (int kk = 0; kk < 4; ++kk) {
        const int cp = (kk * 4 + lg) ^ (lr & 7);  // swizzled 16B chunk
        bf16x8 kf = *(const bf16x8*)(Kb + ((n * 16 + lr) << 8) + (cp << 4));
        sacc[n] = __builtin_amdgcn_mfma_f32_16x16x32_bf16(qf[kk], kf, sacc[n], 0, 0, 0);
      }
    __builtin_amdgcn_s_setprio(0);

    // --- (D) online softmax (rows = w*16 + lg*4 + r, cols = n*16 + lr) ---
    float sv[4][4], tmax[4];
#pragma unroll
    for (int r = 0; r < 4; ++r) tmax[r] = -1e30f;
#pragma unroll
    for (int n = 0; n < 4; ++n)
#pragma unroll
      for (int r = 0; r < 4; ++r) {
        float x = fmaf(sacc[n][r], QK_SCALE, mk[n][r]);
        sv[n][r] = x;
        tmax[r] = fmaxf(tmax[r], x);
      }
#pragma unroll
    for (int r = 0; r < 4; ++r)
#pragma unroll
      for (int off = 1; off < 16; off <<= 1)
        tmax[r] = fmaxf(tmax[r], __shfl_xor(tmax[r], off));
    float corr[4];
#pragma unroll
    for (int r = 0; r < 4; ++r) {
      float mn = fmaxf(mrw[r], tmax[r]);
      corr[r] = __expf(mrw[r] - mn);
      mrw[r] = mn;
    }
    float lsum[4] = {0.f, 0.f, 0.f, 0.f};
#pragma unroll
    for (int n = 0; n < 4; ++n)
#pragma unroll
      for (int r = 0; r < 4; ++r) {
        float p = __expf(sv[n][r] - mrw[r]);
        sv[n][r] = p;
        lsum[r] += p;
      }
#pragma unroll
    for (int r = 0; r < 4; ++r) {
#pragma unroll
      for (int off = 1; off < 16; off <<= 1) lsum[r] += __shfl_xor(lsum[r], off);
      lrw[r] = lrw[r] * corr[r] + lsum[r];
    }
#pragma unroll
    for (int n = 0; n < 8; ++n)
#pragma unroll
      for (int r = 0; r < 4; ++r) acco[n][r] *= corr[r];

    // --- (E) P tile (bf16) -> swizzled LDS; wave-local rows, no barrier ---
#pragma unroll
    for (int n = 0; n < 4; ++n)
#pragma unroll
      for (int r = 0; r < 4; ++r) {
        const int prow  = w * 16 + lg * 4 + r;
        const int pbyte = (n * 32 + lr * 2) ^ (((lg * 4 + r) & 7) << 4);
        *(__bf16*)((char*)Ps + prow * 128 + pbyte) = (__bf16)sv[n][r];
      }
    __asm__ volatile("s_waitcnt lgkmcnt(0)" ::: "memory");
    __builtin_amdgcn_sched_barrier(0);

    // --- (F) O += P V ---
    __builtin_amdgcn_s_setprio(1);
#pragma unroll
    for (int kk = 0; kk < 2; ++kk) {
      const int pcp = (kk * 4 + lg) ^ (lr & 7);
      bf16x8 pa = *(const bf16x8*)(
          (const char*)Ps + (w * 16 + lr) * 128 + (pcp << 4));
#pragma unroll
      for (int n = 0; n < 8; ++n) {
        const int cp = (kk * 4 + lg) ^ (lr & 7);
        bf16x8 vf = *(const bf16x8*)(Vb + ((n * 16 + lr) << 7) + (cp << 4));
        acco[n] = __builtin_amdgcn_mfma_f32_16x16x32_bf16(pa, vf, acco[n], 0, 0, 0);
      }
    }
    __builtin_amdgcn_s_setprio(0);

    // --- (G) publish next buffer / protect current ---
    __syncthreads();
  }

  // --- epilogue: normalize, write attn out as [b, s, h*128+d] bf16 ---
#pragma unroll
  for (int r = 0; r < 4; ++r) {
    const float inv = 1.0f / lrw[r];
    const int srow = q0 + w * 16 + lg * 4 + r;
    const size_t base = ((size_t)b * SEQ + srow) * HDIM + h * HDSZ;
#pragma unroll
    for (int n = 0; n < 8; ++n)
      Out[base + n * 16 + lr] = (__bf16)(acco[n][r] * inv);
  }
}

// ---------------- launcher ----------------
extern "C" void kernel_launch(void* const* d_in, const int* in_sizes, int n_in,
                              void* d_out, int out_size, void* d_ws, size_t ws_size,
                              hipStream_t stream) {
  const float* x    = (const float*)d_in[0];
  const float* mask = (const float*)d_in[1];
  const float* wq   = (const float*)d_in[2];
  const float* wk   = (const float*)d_in[3];
  const float* wv   = (const float*)d_in[4];
  const float* wo   = (const float*)d_in[5];

  constexpr long XN = 4096L * 2048;  // 8388608
  constexpr long WN = 2048L * 2048;  // 4194304

  __bf16* xbf = (__bf16*)d_ws;
  __bf16* wqb = xbf + XN;            // wq;wk;wv;wo contiguous (cast4)
  __bf16* wob = wqb + 3 * WN;
  __bf16* qw  = wqb + 4 * WN;        // Q [b,h,s,d]
  __bf16* kw  = qw + XN;             // K [b,h,s,d]
  __bf16* vtw = kw + XN;             // V^T [b,h,d,s]
  __bf16* aw  = vtw + XN;            // attention output [4096][2048]

  cast_f32_bf16<<<2048, 256, 0, stream>>>(x, xbf, (int)(XN / 4));
  cast4_f32_bf16<<<dim3(256, 4), 256, 0, stream>>>(wq, wk, wv, wo, wqb,
                                                   (int)(WN / 4));

  gemm_qkv<<<dim3(48, 32), 256, 0, stream>>>(xbf, wqb, qw);

  attn_fused<<<dim3(16, 32), 512, 0, stream>>>(qw, kw, vtw, mask, aw);

  gemm_bt_f32<<<dim3(16, 32), 256, 0, stream>>>(aw, wob, (float*)d_out,
                                                4096, 2048, 2048);
}

// Round 6
// 335.924 us; speedup vs baseline: 1.2940x; 1.0821x over previous
//
#include <hip/hip_runtime.h>
#include <stdint.h>

// Problem constants
constexpr int SEQ   = 2048;
constexpr int NHEAD = 16;
constexpr int HDSZ  = 128;   // head dim
constexpr int HDIM  = 2048;  // model dim
constexpr float QK_SCALE = 0.08838834764831845f; // 1/sqrt(128)

typedef __attribute__((ext_vector_type(8))) __bf16 bf16x8;
typedef __attribute__((ext_vector_type(4))) __bf16 bf16x4;
typedef __attribute__((ext_vector_type(2))) __bf16 bf16x2;
typedef __attribute__((ext_vector_type(4))) float  f32x4;

__device__ __forceinline__ void gl_lds16(const void* gptr, void* lptr) {
  // async global->LDS, 16B/lane; LDS dst is wave-uniform base + lane*16
  __builtin_amdgcn_global_load_lds(
      (const __attribute__((address_space(1))) unsigned int*)gptr,
      (__attribute__((address_space(3))) unsigned int*)lptr, 16, 0, 0);
}

// ---------------- fp32 -> bf16 casts ----------------
__global__ __launch_bounds__(256) void cast_f32_bf16(
    const float* __restrict__ in, __bf16* __restrict__ out, int n4) {
  int i = blockIdx.x * blockDim.x + threadIdx.x;
  int stride = gridDim.x * blockDim.x;
  for (; i < n4; i += stride) {
    float4 v = ((const float4*)in)[i];
    bf16x4 o = { (__bf16)v.x, (__bf16)v.y, (__bf16)v.z, (__bf16)v.w };
    ((bf16x4*)out)[i] = o;
  }
}

// 4 weight matrices in one launch; dsts are contiguous at out + y*WN
__global__ __launch_bounds__(256) void cast4_f32_bf16(
    const float* __restrict__ w0, const float* __restrict__ w1,
    const float* __restrict__ w2, const float* __restrict__ w3,
    __bf16* __restrict__ out, int n4) {
  const int y = blockIdx.y;
  const float* src = (y == 0) ? w0 : (y == 1) ? w1 : (y == 2) ? w2 : w3;
  __bf16* dst = out + (size_t)y * (size_t)n4 * 4;
  int i = blockIdx.x * blockDim.x + threadIdx.x;
  int stride = gridDim.x * blockDim.x;
  for (; i < n4; i += stride) {
    float4 v = ((const float4*)src)[i];
    bf16x4 o = { (__bf16)v.x, (__bf16)v.y, (__bf16)v.z, (__bf16)v.w };
    ((bf16x4*)dst)[i] = o;
  }
}

// ---------------- merged QKV GEMM ----------------
// C = A[4096,2048] * W[6144,2048]^T ; W = [wq; wk; wv] contiguous.
// n-tile 0..15 -> Q scatter [b,h,s,d]; 16..31 -> K scatter; 32..47 -> V
// transposed to [b,h,d,s] via half-tile LDS transpose.
// grid FIXED dim3(48,32) = 1536 blocks, XCD swizzle (1536%8==0).
__global__ __launch_bounds__(256) void gemm_qkv(
    const __bf16* __restrict__ A, const __bf16* __restrict__ W,
    __bf16* __restrict__ qkv) {
  constexpr long XN = 4096L * 2048;
  constexpr int K = 2048;
  __shared__ __bf16 As[128 * 32];
  __shared__ __bf16 Bs[128 * 32];
  __shared__ __bf16 Ts[64 * 136];  // V transpose half-tile
  const int tid  = threadIdx.x;
  const int lane = tid & 63;
  const int w    = tid >> 6;
  const int lg   = lane >> 4, lr = lane & 15;
  const int wr   = w >> 1, wc = w & 1;
  const int flat = blockIdx.y * 48 + blockIdx.x;
  const int swz  = (flat & 7) * 192 + (flat >> 3);
  const int mtile = swz & 31, ntile = swz >> 5;  // 0..31, 0..47
  const long mbase = (long)mtile * 128;
  const long nbase = (long)ntile * 128;

  f32x4 acc[4][4];
#pragma unroll
  for (int i = 0; i < 4; ++i)
#pragma unroll
    for (int j = 0; j < 4; ++j) acc[i][j] = (f32x4){0.f, 0.f, 0.f, 0.f};

  const int srow = lane >> 2;
  const int scol = (lane & 3) * 8;

  for (int kt = 0; kt < K; kt += 32) {
#pragma unroll
    for (int i = 0; i < 2; ++i) {
      const int c = w * 2 + i;
      gl_lds16(A + (mbase + c * 16 + srow) * (long)K + kt + scol, &As[c * 512]);
      gl_lds16(W + (nbase + c * 16 + srow) * (long)K + kt + scol, &Bs[c * 512]);
    }
    __syncthreads();
    bf16x8 af[4], bfv[4];
#pragma unroll
    for (int mm = 0; mm < 4; ++mm)
      af[mm] = *(const bf16x8*)&As[(wr * 64 + mm * 16 + lr) * 32 + lg * 8];
#pragma unroll
    for (int nn = 0; nn < 4; ++nn)
      bfv[nn] = *(const bf16x8*)&Bs[(wc * 64 + nn * 16 + lr) * 32 + lg * 8];
    __builtin_amdgcn_s_setprio(1);
#pragma unroll
    for (int nn = 0; nn < 4; ++nn)
#pragma unroll
      for (int mm = 0; mm < 4; ++mm)
        acc[mm][nn] = __builtin_amdgcn_mfma_f32_16x16x32_bf16(
            af[mm], bfv[nn], acc[mm][nn], 0, 0, 0);
    __builtin_amdgcn_s_setprio(0);
    __syncthreads();
  }

  const int  mat = ntile >> 4;              // 0=Q, 1=K, 2=V
  const long nb2 = nbase - (long)mat * 2048;  // col within matrix
  const long b   = mbase >> 11, s0 = mbase & 2047;
  const long h   = nb2 >> 7;
  if (mat < 2) {
    __bf16* out = qkv + (size_t)mat * XN;
#pragma unroll
    for (int mm = 0; mm < 4; ++mm)
#pragma unroll
      for (int nn = 0; nn < 4; ++nn) {
        const long n = nb2 + wc * 64 + nn * 16 + lr;
        const long d = n & 127, hh = n >> 7;
#pragma unroll
        for (int r = 0; r < 4; ++r) {
          const long m = mbase + wr * 64 + mm * 16 + lg * 4 + r;
          out[(((m >> 11) * NHEAD + hh) * SEQ + (m & 2047)) * HDSZ + d] =
              (__bf16)acc[mm][nn][r];
        }
      }
  } else {
    // V: transpose tile to [b, h, d, s] in two 64-row halves
    __bf16* out = qkv + 2 * XN;
#pragma unroll
    for (int dh = 0; dh < 2; ++dh) {
      if (wc == dh) {
#pragma unroll
        for (int mm = 0; mm < 4; ++mm)
#pragma unroll
          for (int nn = 0; nn < 4; ++nn) {
            const int dd = nn * 16 + lr;  // 0..63 within half
#pragma unroll
            for (int r = 0; r < 4; ++r)
              Ts[dd * 136 + wr * 64 + mm * 16 + lg * 4 + r] =
                  (__bf16)acc[mm][nn][r];
          }
      }
      __syncthreads();
#pragma unroll
      for (int it = 0; it < 4; ++it) {
        const int idx = it * 256 + tid;
        const int dd = idx >> 4, c = idx & 15;
        bf16x8 v = *(const bf16x8*)&Ts[dd * 136 + c * 8];
        *(bf16x8*)&out[((b * NHEAD + h) * HDSZ + dh * 64 + dd) * SEQ +
                       s0 + c * 8] = v;
      }
      __syncthreads();
    }
  }
}

// ---------------- plain NT GEMM (fp32 out) for O projection ----------------
__global__ __launch_bounds__(256) void gemm_bt_f32(
    const __bf16* __restrict__ A, const __bf16* __restrict__ B,
    float* __restrict__ C, int M, int N, int K) {
  __shared__ __bf16 As[128 * 32];
  __shared__ __bf16 Bs[128 * 32];
  const int tid  = threadIdx.x;
  const int lane = tid & 63;
  const int w    = tid >> 6;
  const int lg   = lane >> 4, lr = lane & 15;
  const int wr   = w >> 1, wc = w & 1;
  const int flat = blockIdx.y * 16 + blockIdx.x;
  const int swz  = (flat & 7) * 64 + (flat >> 3);
  const long mbase = (long)(swz >> 4) * 128;
  const long nbase = (long)(swz & 15) * 128;

  f32x4 acc[4][4];
#pragma unroll
  for (int i = 0; i < 4; ++i)
#pragma unroll
    for (int j = 0; j < 4; ++j) acc[i][j] = (f32x4){0.f, 0.f, 0.f, 0.f};

  const int srow = lane >> 2;
  const int scol = (lane & 3) * 8;

  for (int kt = 0; kt < K; kt += 32) {
#pragma unroll
    for (int i = 0; i < 2; ++i) {
      const int c = w * 2 + i;
      gl_lds16(A + (mbase + c * 16 + srow) * (long)K + kt + scol, &As[c * 512]);
      gl_lds16(B + (nbase + c * 16 + srow) * (long)K + kt + scol, &Bs[c * 512]);
    }
    __syncthreads();
    bf16x8 af[4], bfv[4];
#pragma unroll
    for (int mm = 0; mm < 4; ++mm)
      af[mm] = *(const bf16x8*)&As[(wr * 64 + mm * 16 + lr) * 32 + lg * 8];
#pragma unroll
    for (int nn = 0; nn < 4; ++nn)
      bfv[nn] = *(const bf16x8*)&Bs[(wc * 64 + nn * 16 + lr) * 32 + lg * 8];
    __builtin_amdgcn_s_setprio(1);
#pragma unroll
    for (int nn = 0; nn < 4; ++nn)
#pragma unroll
      for (int mm = 0; mm < 4; ++mm)
        acc[mm][nn] = __builtin_amdgcn_mfma_f32_16x16x32_bf16(
            af[mm], bfv[nn], acc[mm][nn], 0, 0, 0);
    __builtin_amdgcn_s_setprio(0);
    __syncthreads();
  }

#pragma unroll
  for (int mm = 0; mm < 4; ++mm)
#pragma unroll
    for (int nn = 0; nn < 4; ++nn) {
      const long n = nbase + wc * 64 + nn * 16 + lr;
#pragma unroll
      for (int r = 0; r < 4; ++r) {
        const long m = mbase + wr * 64 + mm * 16 + lg * 4 + r;
        C[m * (long)N + n] = acc[mm][nn][r];
      }
    }
}

// ---------------- fused flash attention v6 ----------------
// QBLK=128, KVBLK=64, 8 waves (512 threads); wave owns 16 q-rows.
// SWAPPED QK^T: sacc = mfma(kf, qf) so each lane holds S[q=lr][k=16 vals]
// lane-locally -> softmax is 2 shfl_xor instead of 16-lane chains (T12 idea).
// Mask loads become float4; P-writes pack to b32 with row-XOR swizzle.
// K/V double-buffered via global_load_lds with pre-swizzled source.
__global__ __launch_bounds__(512, 4) void attn_fused(
    const __bf16* __restrict__ Q, const __bf16* __restrict__ K,
    const __bf16* __restrict__ Vt, const float* __restrict__ mask,
    __bf16* __restrict__ Out) {
  __shared__ __bf16 Ks[2 * 64 * 128];   // [buf][krow][d], swizzled chunks
  __shared__ __bf16 Vs[2 * 128 * 64];   // [buf][d][kcol], swizzled chunks
  __shared__ __bf16 Ps[128 * 64];       // [qrow][k], byte = 2k ^ ((q&7)<<4)

  const int tid  = threadIdx.x;
  const int lane = tid & 63;
  const int w    = tid >> 6;            // 0..7
  const int lg   = lane >> 4, lr = lane & 15;
  const int flat = blockIdx.y * 16 + blockIdx.x;
  const int swz  = (flat & 7) * 64 + (flat >> 3);
  const int bh   = swz >> 4;
  const int b    = bh >> 4, h = bh & 15;
  const int q0   = (swz & 15) * 128;

  const __bf16* Qh = Q  + (size_t)bh * SEQ * HDSZ;
  const __bf16* Kh = K  + (size_t)bh * SEQ * HDSZ;
  const __bf16* Vh = Vt + (size_t)bh * HDSZ * SEQ;  // [d][s]
  const float*  Mb = mask + (size_t)b * SEQ * SEQ;

  // Q fragments (B-operand now: col=lr -> q-row, k=lg*8+i -> d)
  bf16x8 qf[4];
#pragma unroll
  for (int kk = 0; kk < 4; ++kk)
    qf[kk] = *(const bf16x8*)(
        Qh + (size_t)(q0 + w * 16 + lr) * HDSZ + kk * 32 + lg * 8);

  // staging sources (pre-swizzled global addr, linear LDS dest)
  const __bf16* ksrc[2];
  const __bf16* vsrc[2];
#pragma unroll
  for (int i = 0; i < 2; ++i) {
    const int ch = i * 512 + tid;
    const int krow = ch >> 4, kc = ch & 15;
    ksrc[i] = Kh + (size_t)krow * HDSZ + (((kc & 8) | ((kc ^ krow) & 7)) * 8);
    const int vrow = ch >> 3, vc = ch & 7;
    vsrc[i] = Vh + (size_t)vrow * SEQ + (((vc ^ vrow) & 7) * 8);
  }

  float mrw = -1e30f, lrw = 0.f;     // scalar per lane (q = lr)
  f32x4 acco[8];
#pragma unroll
  for (int n = 0; n < 8; ++n) acco[n] = (f32x4){0.f, 0.f, 0.f, 0.f};

  // prologue: stage tile 0 into buffer 0
#pragma unroll
  for (int i = 0; i < 2; ++i) {
    gl_lds16(ksrc[i], &Ks[(i * 512 + w * 64) * 8]);
    gl_lds16(vsrc[i], &Vs[(i * 512 + w * 64) * 8]);
  }
  __syncthreads();

  constexpr int NT = SEQ / 64;
  for (int t = 0; t < NT; ++t) {
    const int cur = t & 1;
    const int kt = t * 64;
    const char* Kb = (const char*)(Ks + cur * (64 * 128));
    const char* Vb = (const char*)(Vs + cur * (128 * 64));

    // --- (A) mask prefetch (float4, k = n*16 + lg*4 + 0..3) ---
    f32x4 mk[4];
#pragma unroll
    for (int n = 0; n < 4; ++n)
      mk[n] = *(const f32x4*)(
          Mb + (size_t)(q0 + w * 16 + lr) * SEQ + kt + n * 16 + lg * 4);
    __builtin_amdgcn_sched_barrier(0);

    // --- (B) STAGE tile t+1 into buf^1 (drained at end barrier) ---
    if (t + 1 < NT) {
      const int nk = kt + 64;
      __bf16* Kn = Ks + (cur ^ 1) * (64 * 128);
      __bf16* Vn = Vs + (cur ^ 1) * (128 * 64);
#pragma unroll
      for (int i = 0; i < 2; ++i) {
        gl_lds16(ksrc[i] + (size_t)nk * HDSZ, &Kn[(i * 512 + w * 64) * 8]);
        gl_lds16(vsrc[i] + nk, &Vn[(i * 512 + w * 64) * 8]);
      }
    }
    __builtin_amdgcn_sched_barrier(0);

    // --- (C) S = K Q^T (SWAPPED: lane gets q=lr, k=n*16+lg*4+r) ---
    f32x4 sacc[4];
#pragma unroll
    for (int n = 0; n < 4; ++n) sacc[n] = (f32x4){0.f, 0.f, 0.f, 0.f};
    __builtin_amdgcn_s_setprio(1);
#pragma unroll
    for (int n = 0; n < 4; ++n)
#pragma unroll
      for (int kk = 0; kk < 4; ++kk) {
        const int cp = (kk * 4 + lg) ^ (lr & 7);  // swizzled 16B chunk
        bf16x8 kf = *(const bf16x8*)(Kb + ((n * 16 + lr) << 8) + (cp << 4));
        sacc[n] = __builtin_amdgcn_mfma_f32_16x16x32_bf16(kf, qf[kk], sacc[n], 0, 0, 0);
      }
    __builtin_amdgcn_s_setprio(0);

    // --- (D) lane-local online softmax (row q = lr, 16 k per lane) ---
    float sv[4][4];
    float tm = -1e30f;
#pragma unroll
    for (int n = 0; n < 4; ++n)
#pragma unroll
      for (int r = 0; r < 4; ++r) {
        float x = fmaf(sacc[n][r], QK_SCALE, mk[n][r]);
        sv[n][r] = x;
        tm = fmaxf(tm, x);
      }
    tm = fmaxf(tm, __shfl_xor(tm, 16));
    tm = fmaxf(tm, __shfl_xor(tm, 32));
    const float mn = fmaxf(mrw, tm);
    const float corr = __expf(mrw - mn);
    mrw = mn;
    float ls = 0.f;
#pragma unroll
    for (int n = 0; n < 4; ++n)
#pragma unroll
      for (int r = 0; r < 4; ++r) {
        float p = __expf(sv[n][r] - mn);
        sv[n][r] = p;
        ls += p;
      }
    ls += __shfl_xor(ls, 16);
    ls += __shfl_xor(ls, 32);
    lrw = lrw * corr + ls;
    // corr broadcast into PV accumulator layout (rows q = lg*4 + r)
    float cb[4];
#pragma unroll
    for (int r = 0; r < 4; ++r) cb[r] = __shfl(corr, lg * 4 + r);
#pragma unroll
    for (int n = 0; n < 8; ++n)
#pragma unroll
      for (int r = 0; r < 4; ++r) acco[n][r] *= cb[r];

    // --- (E) P -> LDS, packed b32 (k pairs are r-adjacent now) ---
#pragma unroll
    for (int n = 0; n < 4; ++n)
#pragma unroll
      for (int rp = 0; rp < 2; ++rp) {
        bf16x2 pk = { (__bf16)sv[n][2 * rp], (__bf16)sv[n][2 * rp + 1] };
        const int pbyte = (n * 32 + lg * 8 + rp * 4) ^ ((lr & 7) << 4);
        *(bf16x2*)((char*)Ps + (w * 16 + lr) * 128 + pbyte) = pk;
      }
    __asm__ volatile("s_waitcnt lgkmcnt(0)" ::: "memory");
    __builtin_amdgcn_sched_barrier(0);

    // --- (F) O += P V ---
    __builtin_amdgcn_s_setprio(1);
#pragma unroll
    for (int kk = 0; kk < 2; ++kk) {
      const int pcp = (kk * 4 + lg) ^ (lr & 7);
      bf16x8 pa = *(const bf16x8*)(
          (const char*)Ps + (w * 16 + lr) * 128 + (pcp << 4));
#pragma unroll
      for (int n = 0; n < 8; ++n) {
        const int cp = (kk * 4 + lg) ^ (lr & 7);
        bf16x8 vf = *(const bf16x8*)(Vb + ((n * 16 + lr) << 7) + (cp << 4));
        acco[n] = __builtin_amdgcn_mfma_f32_16x16x32_bf16(pa, vf, acco[n], 0, 0, 0);
      }
    }
    __builtin_amdgcn_s_setprio(0);

    // --- (G) publish next buffer / protect current ---
    __syncthreads();
  }

  // --- epilogue: normalize, write attn out as [b, s, h*128+d] bf16 ---
  float lb[4];
#pragma unroll
  for (int r = 0; r < 4; ++r) lb[r] = __shfl(lrw, lg * 4 + r);
#pragma unroll
  for (int r = 0; r < 4; ++r) {
    const float inv = 1.0f / lb[r];
    const int srow = q0 + w * 16 + lg * 4 + r;
    const size_t base = ((size_t)b * SEQ + srow) * HDIM + h * HDSZ;
#pragma unroll
    for (int n = 0; n < 8; ++n)
      Out[base + n * 16 + lr] = (__bf16)(acco[n][r] * inv);
  }
}

// ---------------- launcher ----------------
extern "C" void kernel_launch(void* const* d_in, const int* in_sizes, int n_in,
                              void* d_out, int out_size, void* d_ws, size_t ws_size,
                              hipStream_t stream) {
  const float* x    = (const float*)d_in[0];
  const float* mask = (const float*)d_in[1];
  const float* wq   = (const float*)d_in[2];
  const float* wk   = (const float*)d_in[3];
  const float* wv   = (const float*)d_in[4];
  const float* wo   = (const float*)d_in[5];

  constexpr long XN = 4096L * 2048;  // 8388608
  constexpr long WN = 2048L * 2048;  // 4194304

  __bf16* xbf = (__bf16*)d_ws;
  __bf16* wqb = xbf + XN;            // wq;wk;wv;wo contiguous (cast4)
  __bf16* wob = wqb + 3 * WN;
  __bf16* qw  = wqb + 4 * WN;        // Q [b,h,s,d]
  __bf16* kw  = qw + XN;             // K [b,h,s,d]
  __bf16* vtw = kw + XN;             // V^T [b,h,d,s]
  __bf16* aw  = vtw + XN;            // attention output [4096][2048]

  cast_f32_bf16<<<2048, 256, 0, stream>>>(x, xbf, (int)(XN / 4));
  cast4_f32_bf16<<<dim3(256, 4), 256, 0, stream>>>(wq, wk, wv, wo, wqb,
                                                   (int)(WN / 4));

  gemm_qkv<<<dim3(48, 32), 256, 0, stream>>>(xbf, wqb, qw);

  attn_fused<<<dim3(16, 32), 512, 0, stream>>>(qw, kw, vtw, mask, aw);

  gemm_bt_f32<<<dim3(16, 32), 256, 0, stream>>>(aw, wob, (float*)d_out,
                                                4096, 2048, 2048);
}

// Round 7
// 335.765 us; speedup vs baseline: 1.2946x; 1.0005x over previous
//
#include <hip/hip_runtime.h>
#include <stdint.h>

// Problem constants
constexpr int SEQ   = 2048;
constexpr int NHEAD = 16;
constexpr int HDSZ  = 128;   // head dim
constexpr int HDIM  = 2048;  // model dim
constexpr float QK_SCALE = 0.08838834764831845f; // 1/sqrt(128)

typedef __attribute__((ext_vector_type(8))) __bf16 bf16x8;
typedef __attribute__((ext_vector_type(4))) __bf16 bf16x4;
typedef __attribute__((ext_vector_type(2))) __bf16 bf16x2;
typedef __attribute__((ext_vector_type(4))) float  f32x4;

__device__ __forceinline__ void gl_lds16(const void* gptr, void* lptr) {
  // async global->LDS, 16B/lane; LDS dst is wave-uniform base + lane*16
  __builtin_amdgcn_global_load_lds(
      (const __attribute__((address_space(1))) unsigned int*)gptr,
      (__attribute__((address_space(3))) unsigned int*)lptr, 16, 0, 0);
}

// ---------------- fp32 -> bf16 casts ----------------
__global__ __launch_bounds__(256) void cast_f32_bf16(
    const float* __restrict__ in, __bf16* __restrict__ out, int n4) {
  int i = blockIdx.x * blockDim.x + threadIdx.x;
  int stride = gridDim.x * blockDim.x;
  for (; i < n4; i += stride) {
    float4 v = ((const float4*)in)[i];
    bf16x4 o = { (__bf16)v.x, (__bf16)v.y, (__bf16)v.z, (__bf16)v.w };
    ((bf16x4*)out)[i] = o;
  }
}

// 4 weight matrices in one launch; dsts are contiguous at out + y*WN
__global__ __launch_bounds__(256) void cast4_f32_bf16(
    const float* __restrict__ w0, const float* __restrict__ w1,
    const float* __restrict__ w2, const float* __restrict__ w3,
    __bf16* __restrict__ out, int n4) {
  const int y = blockIdx.y;
  const float* src = (y == 0) ? w0 : (y == 1) ? w1 : (y == 2) ? w2 : w3;
  __bf16* dst = out + (size_t)y * (size_t)n4 * 4;
  int i = blockIdx.x * blockDim.x + threadIdx.x;
  int stride = gridDim.x * blockDim.x;
  for (; i < n4; i += stride) {
    float4 v = ((const float4*)src)[i];
    bf16x4 o = { (__bf16)v.x, (__bf16)v.y, (__bf16)v.z, (__bf16)v.w };
    ((bf16x4*)dst)[i] = o;
  }
}

// ---------------- merged QKV GEMM ----------------
// C = A[4096,2048] * W[6144,2048]^T ; W = [wq; wk; wv] contiguous.
// LDS is UNIONED: K-loop uses As+Bs (16KB); epilogue reuses the same
// memory as Ts (17KB transpose/staging buffer). 17.4KB total (was 33.8KB)
// -> occupancy no longer LDS-capped for Q/K blocks.
// All three outputs staged through Ts in two 64-row halves and written as
// coalesced b128 rows: Q,K -> [b,h,s,d] (Ts[s][d]); V -> [b,h,d,s] (Ts[d][s]).
// grid FIXED dim3(48,32) = 1536 blocks, XCD swizzle (1536%8==0).
__global__ __launch_bounds__(256) void gemm_qkv(
    const __bf16* __restrict__ A, const __bf16* __restrict__ W,
    __bf16* __restrict__ qkv) {
  constexpr long XN = 4096L * 2048;
  constexpr int K = 2048;
  __shared__ __align__(16) char smem[64 * 136 * 2];  // 17408 B
  __bf16* As = (__bf16*)smem;             // [128][32] during K-loop
  __bf16* Bs = As + 128 * 32;             // [128][32] during K-loop
  __bf16* Ts = (__bf16*)smem;             // [64][136] during epilogue

  const int tid  = threadIdx.x;
  const int lane = tid & 63;
  const int w    = tid >> 6;
  const int lg   = lane >> 4, lr = lane & 15;
  const int wr   = w >> 1, wc = w & 1;
  const int flat = blockIdx.y * 48 + blockIdx.x;
  const int swz  = (flat & 7) * 192 + (flat >> 3);
  const int mtile = swz & 31, ntile = swz >> 5;  // 0..31, 0..47
  const long mbase = (long)mtile * 128;
  const long nbase = (long)ntile * 128;

  f32x4 acc[4][4];
#pragma unroll
  for (int i = 0; i < 4; ++i)
#pragma unroll
    for (int j = 0; j < 4; ++j) acc[i][j] = (f32x4){0.f, 0.f, 0.f, 0.f};

  const int srow = lane >> 2;
  const int scol = (lane & 3) * 8;

  for (int kt = 0; kt < K; kt += 32) {
#pragma unroll
    for (int i = 0; i < 2; ++i) {
      const int c = w * 2 + i;
      gl_lds16(A + (mbase + c * 16 + srow) * (long)K + kt + scol, &As[c * 512]);
      gl_lds16(W + (nbase + c * 16 + srow) * (long)K + kt + scol, &Bs[c * 512]);
    }
    __syncthreads();
    bf16x8 af[4], bfv[4];
#pragma unroll
    for (int mm = 0; mm < 4; ++mm)
      af[mm] = *(const bf16x8*)&As[(wr * 64 + mm * 16 + lr) * 32 + lg * 8];
#pragma unroll
    for (int nn = 0; nn < 4; ++nn)
      bfv[nn] = *(const bf16x8*)&Bs[(wc * 64 + nn * 16 + lr) * 32 + lg * 8];
    __builtin_amdgcn_s_setprio(1);
#pragma unroll
    for (int nn = 0; nn < 4; ++nn)
#pragma unroll
      for (int mm = 0; mm < 4; ++mm)
        acc[mm][nn] = __builtin_amdgcn_mfma_f32_16x16x32_bf16(
            af[mm], bfv[nn], acc[mm][nn], 0, 0, 0);
    __builtin_amdgcn_s_setprio(0);
    __syncthreads();  // also orders last As/Bs reads before Ts reuse
  }

  // Epilogue. D layout (m89-verified): col = lane&15, row = (lane>>4)*4 + r
  const int  mat = ntile >> 4;                // 0=Q, 1=K, 2=V
  const long nb2 = nbase - (long)mat * 2048;  // col within matrix
  const long b   = mbase >> 11, s0 = mbase & 2047;
  const long h   = nb2 >> 7;                  // one head per block

  if (mat < 2) {
    // Q,K: stage Ts[s_local][d], write coalesced rows of [b,h,s,:]
    __bf16* out = qkv + (size_t)mat * XN;
#pragma unroll
    for (int dh = 0; dh < 2; ++dh) {
      if (wr == dh) {
#pragma unroll
        for (int mm = 0; mm < 4; ++mm)
#pragma unroll
          for (int nn = 0; nn < 4; ++nn) {
            const int d = wc * 64 + nn * 16 + lr;
#pragma unroll
            for (int r = 0; r < 4; ++r)
              Ts[(mm * 16 + lg * 4 + r) * 136 + d] = (__bf16)acc[mm][nn][r];
          }
      }
      __syncthreads();
#pragma unroll
      for (int it = 0; it < 4; ++it) {
        const int idx = it * 256 + tid;
        const int row = idx >> 4, c = idx & 15;
        bf16x8 v = *(const bf16x8*)&Ts[row * 136 + c * 8];
        *(bf16x8*)&out[((b * NHEAD + h) * SEQ + s0 + dh * 64 + row) * HDSZ +
                       c * 8] = v;
      }
      __syncthreads();
    }
  } else {
    // V: stage Ts[d_local][s], write coalesced rows of [b,h,d,:]
    __bf16* out = qkv + 2 * XN;
#pragma unroll
    for (int dh = 0; dh < 2; ++dh) {
      if (wc == dh) {
#pragma unroll
        for (int mm = 0; mm < 4; ++mm)
#pragma unroll
          for (int nn = 0; nn < 4; ++nn) {
            const int dd = nn * 16 + lr;  // 0..63 within half
            bf16x4 pk = { (__bf16)acc[mm][nn][0], (__bf16)acc[mm][nn][1],
                          (__bf16)acc[mm][nn][2], (__bf16)acc[mm][nn][3] };
            *(bf16x4*)&Ts[dd * 136 + wr * 64 + mm * 16 + lg * 4] = pk;
          }
      }
      __syncthreads();
#pragma unroll
      for (int it = 0; it < 4; ++it) {
        const int idx = it * 256 + tid;
        const int dd = idx >> 4, c = idx & 15;
        bf16x8 v = *(const bf16x8*)&Ts[dd * 136 + c * 8];
        *(bf16x8*)&out[((b * NHEAD + h) * HDSZ + dh * 64 + dd) * SEQ +
                       s0 + c * 8] = v;
      }
      __syncthreads();
    }
  }
}

// ---------------- plain NT GEMM (fp32 out) for O projection ----------------
__global__ __launch_bounds__(256) void gemm_bt_f32(
    const __bf16* __restrict__ A, const __bf16* __restrict__ B,
    float* __restrict__ C, int M, int N, int K) {
  __shared__ __bf16 As[128 * 32];
  __shared__ __bf16 Bs[128 * 32];
  const int tid  = threadIdx.x;
  const int lane = tid & 63;
  const int w    = tid >> 6;
  const int lg   = lane >> 4, lr = lane & 15;
  const int wr   = w >> 1, wc = w & 1;
  const int flat = blockIdx.y * 16 + blockIdx.x;
  const int swz  = (flat & 7) * 64 + (flat >> 3);
  const long mbase = (long)(swz >> 4) * 128;
  const long nbase = (long)(swz & 15) * 128;

  f32x4 acc[4][4];
#pragma unroll
  for (int i = 0; i < 4; ++i)
#pragma unroll
    for (int j = 0; j < 4; ++j) acc[i][j] = (f32x4){0.f, 0.f, 0.f, 0.f};

  const int srow = lane >> 2;
  const int scol = (lane & 3) * 8;

  for (int kt = 0; kt < K; kt += 32) {
#pragma unroll
    for (int i = 0; i < 2; ++i) {
      const int c = w * 2 + i;
      gl_lds16(A + (mbase + c * 16 + srow) * (long)K + kt + scol, &As[c * 512]);
      gl_lds16(B + (nbase + c * 16 + srow) * (long)K + kt + scol, &Bs[c * 512]);
    }
    __syncthreads();
    bf16x8 af[4], bfv[4];
#pragma unroll
    for (int mm = 0; mm < 4; ++mm)
      af[mm] = *(const bf16x8*)&As[(wr * 64 + mm * 16 + lr) * 32 + lg * 8];
#pragma unroll
    for (int nn = 0; nn < 4; ++nn)
      bfv[nn] = *(const bf16x8*)&Bs[(wc * 64 + nn * 16 + lr) * 32 + lg * 8];
    __builtin_amdgcn_s_setprio(1);
#pragma unroll
    for (int nn = 0; nn < 4; ++nn)
#pragma unroll
      for (int mm = 0; mm < 4; ++mm)
        acc[mm][nn] = __builtin_amdgcn_mfma_f32_16x16x32_bf16(
            af[mm], bfv[nn], acc[mm][nn], 0, 0, 0);
    __builtin_amdgcn_s_setprio(0);
    __syncthreads();
  }

#pragma unroll
  for (int mm = 0; mm < 4; ++mm)
#pragma unroll
    for (int nn = 0; nn < 4; ++nn) {
      const long n = nbase + wc * 64 + nn * 16 + lr;
#pragma unroll
      for (int r = 0; r < 4; ++r) {
        const long m = mbase + wr * 64 + mm * 16 + lg * 4 + r;
        C[m * (long)N + n] = acc[mm][nn][r];
      }
    }
}

// ---------------- fused flash attention v6 ----------------
// QBLK=128, KVBLK=64, 8 waves (512 threads); wave owns 16 q-rows.
// SWAPPED QK^T: sacc = mfma(kf, qf) so each lane holds S[q=lr][k=16 vals]
// lane-locally -> softmax is 2 shfl_xor instead of 16-lane chains (T12 idea).
// Mask loads become float4; P-writes pack to b32 with row-XOR swizzle.
// K/V double-buffered via global_load_lds with pre-swizzled source.
__global__ __launch_bounds__(512, 4) void attn_fused(
    const __bf16* __restrict__ Q, const __bf16* __restrict__ K,
    const __bf16* __restrict__ Vt, const float* __restrict__ mask,
    __bf16* __restrict__ Out) {
  __shared__ __bf16 Ks[2 * 64 * 128];   // [buf][krow][d], swizzled chunks
  __shared__ __bf16 Vs[2 * 128 * 64];   // [buf][d][kcol], swizzled chunks
  __shared__ __bf16 Ps[128 * 64];       // [qrow][k], byte = 2k ^ ((q&7)<<4)

  const int tid  = threadIdx.x;
  const int lane = tid & 63;
  const int w    = tid >> 6;            // 0..7
  const int lg   = lane >> 4, lr = lane & 15;
  const int flat = blockIdx.y * 16 + blockIdx.x;
  const int swz  = (flat & 7) * 64 + (flat >> 3);
  const int bh   = swz >> 4;
  const int b    = bh >> 4, h = bh & 15;
  const int q0   = (swz & 15) * 128;

  const __bf16* Qh = Q  + (size_t)bh * SEQ * HDSZ;
  const __bf16* Kh = K  + (size_t)bh * SEQ * HDSZ;
  const __bf16* Vh = Vt + (size_t)bh * HDSZ * SEQ;  // [d][s]
  const float*  Mb = mask + (size_t)b * SEQ * SEQ;

  // Q fragments (B-operand now: col=lr -> q-row, k=lg*8+i -> d)
  bf16x8 qf[4];
#pragma unroll
  for (int kk = 0; kk < 4; ++kk)
    qf[kk] = *(const bf16x8*)(
        Qh + (size_t)(q0 + w * 16 + lr) * HDSZ + kk * 32 + lg * 8);

  // staging sources (pre-swizzled global addr, linear LDS dest)
  const __bf16* ksrc[2];
  const __bf16* vsrc[2];
#pragma unroll
  for (int i = 0; i < 2; ++i) {
    const int ch = i * 512 + tid;
    const int krow = ch >> 4, kc = ch & 15;
    ksrc[i] = Kh + (size_t)krow * HDSZ + (((kc & 8) | ((kc ^ krow) & 7)) * 8);
    const int vrow = ch >> 3, vc = ch & 7;
    vsrc[i] = Vh + (size_t)vrow * SEQ + (((vc ^ vrow) & 7) * 8);
  }

  float mrw = -1e30f, lrw = 0.f;     // scalar per lane (q = lr)
  f32x4 acco[8];
#pragma unroll
  for (int n = 0; n < 8; ++n) acco[n] = (f32x4){0.f, 0.f, 0.f, 0.f};

  // prologue: stage tile 0 into buffer 0
#pragma unroll
  for (int i = 0; i < 2; ++i) {
    gl_lds16(ksrc[i], &Ks[(i * 512 + w * 64) * 8]);
    gl_lds16(vsrc[i], &Vs[(i * 512 + w * 64) * 8]);
  }
  __syncthreads();

  constexpr int NT = SEQ / 64;
  for (int t = 0; t < NT; ++t) {
    const int cur = t & 1;
    const int kt = t * 64;
    const char* Kb = (const char*)(Ks + cur * (64 * 128));
    const char* Vb = (const char*)(Vs + cur * (128 * 64));

    // --- (A) mask prefetch (float4, k = n*16 + lg*4 + 0..3) ---
    f32x4 mk[4];
#pragma unroll
    for (int n = 0; n < 4; ++n)
      mk[n] = *(const f32x4*)(
          Mb + (size_t)(q0 + w * 16 + lr) * SEQ + kt + n * 16 + lg * 4);
    __builtin_amdgcn_sched_barrier(0);

    // --- (B) STAGE tile t+1 into buf^1 (drained at end barrier) ---
    if (t + 1 < NT) {
      const int nk = kt + 64;
      __bf16* Kn = Ks + (cur ^ 1) * (64 * 128);
      __bf16* Vn = Vs + (cur ^ 1) * (128 * 64);
#pragma unroll
      for (int i = 0; i < 2; ++i) {
        gl_lds16(ksrc[i] + (size_t)nk * HDSZ, &Kn[(i * 512 + w * 64) * 8]);
        gl_lds16(vsrc[i] + nk, &Vn[(i * 512 + w * 64) * 8]);
      }
    }
    __builtin_amdgcn_sched_barrier(0);

    // --- (C) S = K Q^T (SWAPPED: lane gets q=lr, k=n*16+lg*4+r) ---
    f32x4 sacc[4];
#pragma unroll
    for (int n = 0; n < 4; ++n) sacc[n] = (f32x4){0.f, 0.f, 0.f, 0.f};
    __builtin_amdgcn_s_setprio(1);
#pragma unroll
    for (int n = 0; n < 4; ++n)
#pragma unroll
      for (int kk = 0; kk < 4; ++kk) {
        const int cp = (kk * 4 + lg) ^ (lr & 7);  // swizzled 16B chunk
        bf16x8 kf = *(const bf16x8*)(Kb + ((n * 16 + lr) << 8) + (cp << 4));
        sacc[n] = __builtin_amdgcn_mfma_f32_16x16x32_bf16(kf, qf[kk], sacc[n], 0, 0, 0);
      }
    __builtin_amdgcn_s_setprio(0);

    // --- (D) lane-local online softmax (row q = lr, 16 k per lane) ---
    float sv[4][4];
    float tm = -1e30f;
#pragma unroll
    for (int n = 0; n < 4; ++n)
#pragma unroll
      for (int r = 0; r < 4; ++r) {
        float x = fmaf(sacc[n][r], QK_SCALE, mk[n][r]);
        sv[n][r] = x;
        tm = fmaxf(tm, x);
      }
    tm = fmaxf(tm, __shfl_xor(tm, 16));
    tm = fmaxf(tm, __shfl_xor(tm, 32));
    const float mn = fmaxf(mrw, tm);
    const float corr = __expf(mrw - mn);
    mrw = mn;
    float ls = 0.f;
#pragma unroll
    for (int n = 0; n < 4; ++n)
#pragma unroll
      for (int r = 0; r < 4; ++r) {
        float p = __expf(sv[n][r] - mn);
        sv[n][r] = p;
        ls += p;
      }
    ls += __shfl_xor(ls, 16);
    ls += __shfl_xor(ls, 32);
    lrw = lrw * corr + ls;
    // corr broadcast into PV accumulator layout (rows q = lg*4 + r)
    float cb[4];
#pragma unroll
    for (int r = 0; r < 4; ++r) cb[r] = __shfl(corr, lg * 4 + r);
#pragma unroll
    for (int n = 0; n < 8; ++n)
#pragma unroll
      for (int r = 0; r < 4; ++r) acco[n][r] *= cb[r];

    // --- (E) P -> LDS, packed b32 (k pairs are r-adjacent now) ---
#pragma unroll
    for (int n = 0; n < 4; ++n)
#pragma unroll
      for (int rp = 0; rp < 2; ++rp) {
        bf16x2 pk = { (__bf16)sv[n][2 * rp], (__bf16)sv[n][2 * rp + 1] };
        const int pbyte = (n * 32 + lg * 8 + rp * 4) ^ ((lr & 7) << 4);
        *(bf16x2*)((char*)Ps + (w * 16 + lr) * 128 + pbyte) = pk;
      }
    __asm__ volatile("s_waitcnt lgkmcnt(0)" ::: "memory");
    __builtin_amdgcn_sched_barrier(0);

    // --- (F) O += P V ---
    __builtin_amdgcn_s_setprio(1);
#pragma unroll
    for (int kk = 0; kk < 2; ++kk) {
      const int pcp = (kk * 4 + lg) ^ (lr & 7);
      bf16x8 pa = *(const bf16x8*)(
          (const char*)Ps + (w * 16 + lr) * 128 + (pcp << 4));
#pragma unroll
      for (int n = 0; n < 8; ++n) {
        const int cp = (kk * 4 + lg) ^ (lr & 7);
        bf16x8 vf = *(const bf16x8*)(Vb + ((n * 16 + lr) << 7) + (cp << 4));
        acco[n] = __builtin_amdgcn_mfma_f32_16x16x32_bf16(pa, vf, acco[n], 0, 0, 0);
      }
    }
    __builtin_amdgcn_s_setprio(0);

    // --- (G) publish next buffer / protect current ---
    __syncthreads();
  }

  // --- epilogue: normalize, write attn out as [b, s, h*128+d] bf16 ---
  float lb[4];
#pragma unroll
  for (int r = 0; r < 4; ++r) lb[r] = __shfl(lrw, lg * 4 + r);
#pragma unroll
  for (int r = 0; r < 4; ++r) {
    const float inv = 1.0f / lb[r];
    const int srow = q0 + w * 16 + lg * 4 + r;
    const size_t base = ((size_t)b * SEQ + srow) * HDIM + h * HDSZ;
#pragma unroll
    for (int n = 0; n < 8; ++n)
      Out[base + n * 16 + lr] = (__bf16)(acco[n][r] * inv);
  }
}

// ---------------- launcher ----------------
extern "C" void kernel_launch(void* const* d_in, const int* in_sizes, int n_in,
                              void* d_out, int out_size, void* d_ws, size_t ws_size,
                              hipStream_t stream) {
  const float* x    = (const float*)d_in[0];
  const float* mask = (const float*)d_in[1];
  const float* wq   = (const float*)d_in[2];
  const float* wk   = (const float*)d_in[3];
  const float* wv   = (const float*)d_in[4];
  const float* wo   = (const float*)d_in[5];

  constexpr long XN = 4096L * 2048;  // 8388608
  constexpr long WN = 2048L * 2048;  // 4194304

  __bf16* xbf = (__bf16*)d_ws;
  __bf16* wqb = xbf + XN;            // wq;wk;wv;wo contiguous (cast4)
  __bf16* wob = wqb + 3 * WN;
  __bf16* qw  = wqb + 4 * WN;        // Q [b,h,s,d]
  __bf16* kw  = qw + XN;             // K [b,h,s,d]
  __bf16* vtw = kw + XN;             // V^T [b,h,d,s]
  __bf16* aw  = vtw + XN;            // attention output [4096][2048]

  cast_f32_bf16<<<2048, 256, 0, stream>>>(x, xbf, (int)(XN / 4));
  cast4_f32_bf16<<<dim3(256, 4), 256, 0, stream>>>(wq, wk, wv, wo, wqb,
                                                   (int)(WN / 4));

  gemm_qkv<<<dim3(48, 32), 256, 0, stream>>>(xbf, wqb, qw);

  attn_fused<<<dim3(16, 32), 512, 0, stream>>>(qw, kw, vtw, mask, aw);

  gemm_bt_f32<<<dim3(16, 32), 256, 0, stream>>>(aw, wob, (float*)d_out,
                                                4096, 2048, 2048);
}

// Round 8
// 326.365 us; speedup vs baseline: 1.3319x; 1.0288x over previous
//
#include <hip/hip_runtime.h>
#include <stdint.h>

// Problem constants
constexpr int SEQ   = 2048;
constexpr int NHEAD = 16;
constexpr int HDSZ  = 128;   // head dim
constexpr int HDIM  = 2048;  // model dim
constexpr float QK_SCALE = 0.08838834764831845f; // 1/sqrt(128)

typedef __attribute__((ext_vector_type(8))) __bf16 bf16x8;
typedef __attribute__((ext_vector_type(4))) __bf16 bf16x4;
typedef __attribute__((ext_vector_type(2))) __bf16 bf16x2;
typedef __attribute__((ext_vector_type(4))) float  f32x4;

__device__ __forceinline__ void gl_lds16(const void* gptr, void* lptr) {
  // async global->LDS, 16B/lane; LDS dst is wave-uniform base + lane*16
  __builtin_amdgcn_global_load_lds(
      (const __attribute__((address_space(1))) unsigned int*)gptr,
      (__attribute__((address_space(3))) unsigned int*)lptr, 16, 0, 0);
}

// ---------------- fp32 -> bf16 casts ----------------
__global__ __launch_bounds__(256) void cast_f32_bf16(
    const float* __restrict__ in, __bf16* __restrict__ out, int n4) {
  int i = blockIdx.x * blockDim.x + threadIdx.x;
  int stride = gridDim.x * blockDim.x;
  for (; i < n4; i += stride) {
    float4 v = ((const float4*)in)[i];
    bf16x4 o = { (__bf16)v.x, (__bf16)v.y, (__bf16)v.z, (__bf16)v.w };
    ((bf16x4*)out)[i] = o;
  }
}

// 4 weight matrices in one launch; dsts are contiguous at out + y*WN
__global__ __launch_bounds__(256) void cast4_f32_bf16(
    const float* __restrict__ w0, const float* __restrict__ w1,
    const float* __restrict__ w2, const float* __restrict__ w3,
    __bf16* __restrict__ out, int n4) {
  const int y = blockIdx.y;
  const float* src = (y == 0) ? w0 : (y == 1) ? w1 : (y == 2) ? w2 : w3;
  __bf16* dst = out + (size_t)y * (size_t)n4 * 4;
  int i = blockIdx.x * blockDim.x + threadIdx.x;
  int stride = gridDim.x * blockDim.x;
  for (; i < n4; i += stride) {
    float4 v = ((const float4*)src)[i];
    bf16x4 o = { (__bf16)v.x, (__bf16)v.y, (__bf16)v.z, (__bf16)v.w };
    ((bf16x4*)dst)[i] = o;
  }
}

// ---------------- merged QKV GEMM (T3 2-phase double-buffered) ----------------
// C = A[4096,2048] * W[6144,2048]^T ; W = [wq; wk; wv] contiguous.
// LDS: 2 x 16KB double buffer (As|Bs per buffer). STAGE(t+1) issued BEFORE
// compute(t); single barrier per iteration drains it after the MFMA phase
// -> global_load_lds latency hidden under compute (attn-R3 pattern).
// Epilogue Ts (17KB transpose/staging buffer) unions with the dead buffers.
// Outputs staged through Ts, written as coalesced b128 rows:
// Q,K -> [b,h,s,d]; V -> [b,h,d,s].
// grid FIXED dim3(48,32) = 1536 blocks, XCD swizzle (1536%8==0).
__global__ __launch_bounds__(256) void gemm_qkv(
    const __bf16* __restrict__ A, const __bf16* __restrict__ W,
    __bf16* __restrict__ qkv) {
  constexpr long XN = 4096L * 2048;
  constexpr int K = 2048;
  __shared__ __align__(16) char smem[2 * 16384];  // [buf][As 8K | Bs 8K]
  __bf16* Ts = (__bf16*)smem;                     // [64][136] epilogue reuse

  const int tid  = threadIdx.x;
  const int lane = tid & 63;
  const int w    = tid >> 6;
  const int lg   = lane >> 4, lr = lane & 15;
  const int wr   = w >> 1, wc = w & 1;
  const int flat = blockIdx.y * 48 + blockIdx.x;
  const int swz  = (flat & 7) * 192 + (flat >> 3);
  const int mtile = swz & 31, ntile = swz >> 5;  // 0..31, 0..47
  const long mbase = (long)mtile * 128;
  const long nbase = (long)ntile * 128;

  f32x4 acc[4][4];
#pragma unroll
  for (int i = 0; i < 4; ++i)
#pragma unroll
    for (int j = 0; j < 4; ++j) acc[i][j] = (f32x4){0.f, 0.f, 0.f, 0.f};

  const int srow = lane >> 2;
  const int scol = (lane & 3) * 8;

  auto stage = [&](int buf, int kt) {
    __bf16* As = (__bf16*)(smem + buf * 16384);
    __bf16* Bs = As + 128 * 32;
#pragma unroll
    for (int i = 0; i < 2; ++i) {
      const int c = w * 2 + i;
      gl_lds16(A + (mbase + c * 16 + srow) * (long)K + kt + scol, &As[c * 512]);
      gl_lds16(W + (nbase + c * 16 + srow) * (long)K + kt + scol, &Bs[c * 512]);
    }
  };

  // prologue
  stage(0, 0);
  __syncthreads();

  constexpr int NTK = K / 32;
  for (int t = 0; t < NTK; ++t) {
    const int cur = t & 1;
    if (t + 1 < NTK) stage(cur ^ 1, (t + 1) * 32);  // flies during compute
    __builtin_amdgcn_sched_barrier(0);
    const __bf16* As = (const __bf16*)(smem + cur * 16384);
    const __bf16* Bs = As + 128 * 32;
    bf16x8 af[4], bfv[4];
#pragma unroll
    for (int mm = 0; mm < 4; ++mm)
      af[mm] = *(const bf16x8*)&As[(wr * 64 + mm * 16 + lr) * 32 + lg * 8];
#pragma unroll
    for (int nn = 0; nn < 4; ++nn)
      bfv[nn] = *(const bf16x8*)&Bs[(wc * 64 + nn * 16 + lr) * 32 + lg * 8];
    __builtin_amdgcn_s_setprio(1);
#pragma unroll
    for (int nn = 0; nn < 4; ++nn)
#pragma unroll
      for (int mm = 0; mm < 4; ++mm)
        acc[mm][nn] = __builtin_amdgcn_mfma_f32_16x16x32_bf16(
            af[mm], bfv[nn], acc[mm][nn], 0, 0, 0);
    __builtin_amdgcn_s_setprio(0);
    __syncthreads();  // drains this iter's STAGE; publishes buf^1
  }

  // Epilogue. D layout (m89-verified): col = lane&15, row = (lane>>4)*4 + r
  const int  mat = ntile >> 4;                // 0=Q, 1=K, 2=V
  const long nb2 = nbase - (long)mat * 2048;  // col within matrix
  const long b   = mbase >> 11, s0 = mbase & 2047;
  const long h   = nb2 >> 7;                  // one head per block

  if (mat < 2) {
    // Q,K: stage Ts[s_local][d], write coalesced rows of [b,h,s,:]
    __bf16* out = qkv + (size_t)mat * XN;
#pragma unroll
    for (int dh = 0; dh < 2; ++dh) {
      if (wr == dh) {
#pragma unroll
        for (int mm = 0; mm < 4; ++mm)
#pragma unroll
          for (int nn = 0; nn < 4; ++nn) {
            const int d = wc * 64 + nn * 16 + lr;
#pragma unroll
            for (int r = 0; r < 4; ++r)
              Ts[(mm * 16 + lg * 4 + r) * 136 + d] = (__bf16)acc[mm][nn][r];
          }
      }
      __syncthreads();
#pragma unroll
      for (int it = 0; it < 4; ++it) {
        const int idx = it * 256 + tid;
        const int row = idx >> 4, c = idx & 15;
        bf16x8 v = *(const bf16x8*)&Ts[row * 136 + c * 8];
        *(bf16x8*)&out[((b * NHEAD + h) * SEQ + s0 + dh * 64 + row) * HDSZ +
                       c * 8] = v;
      }
      __syncthreads();
    }
  } else {
    // V: stage Ts[d_local][s], write coalesced rows of [b,h,d,:]
    __bf16* out = qkv + 2 * XN;
#pragma unroll
    for (int dh = 0; dh < 2; ++dh) {
      if (wc == dh) {
#pragma unroll
        for (int mm = 0; mm < 4; ++mm)
#pragma unroll
          for (int nn = 0; nn < 4; ++nn) {
            const int dd = nn * 16 + lr;  // 0..63 within half
            bf16x4 pk = { (__bf16)acc[mm][nn][0], (__bf16)acc[mm][nn][1],
                          (__bf16)acc[mm][nn][2], (__bf16)acc[mm][nn][3] };
            *(bf16x4*)&Ts[dd * 136 + wr * 64 + mm * 16 + lg * 4] = pk;
          }
      }
      __syncthreads();
#pragma unroll
      for (int it = 0; it < 4; ++it) {
        const int idx = it * 256 + tid;
        const int dd = idx >> 4, c = idx & 15;
        bf16x8 v = *(const bf16x8*)&Ts[dd * 136 + c * 8];
        *(bf16x8*)&out[((b * NHEAD + h) * HDSZ + dh * 64 + dd) * SEQ +
                       s0 + c * 8] = v;
      }
      __syncthreads();
    }
  }
}

// ---------------- O-projection GEMM (fp32 out, T3 2-phase dbuf) ----------------
__global__ __launch_bounds__(256) void gemm_bt_f32(
    const __bf16* __restrict__ A, const __bf16* __restrict__ B,
    float* __restrict__ C, int M, int N, int K) {
  __shared__ __align__(16) char smem[2 * 16384];  // [buf][As 8K | Bs 8K]
  const int tid  = threadIdx.x;
  const int lane = tid & 63;
  const int w    = tid >> 6;
  const int lg   = lane >> 4, lr = lane & 15;
  const int wr   = w >> 1, wc = w & 1;
  const int flat = blockIdx.y * 16 + blockIdx.x;
  const int swz  = (flat & 7) * 64 + (flat >> 3);
  const long mbase = (long)(swz >> 4) * 128;
  const long nbase = (long)(swz & 15) * 128;

  f32x4 acc[4][4];
#pragma unroll
  for (int i = 0; i < 4; ++i)
#pragma unroll
    for (int j = 0; j < 4; ++j) acc[i][j] = (f32x4){0.f, 0.f, 0.f, 0.f};

  const int srow = lane >> 2;
  const int scol = (lane & 3) * 8;

  auto stage = [&](int buf, int kt) {
    __bf16* As = (__bf16*)(smem + buf * 16384);
    __bf16* Bs = As + 128 * 32;
#pragma unroll
    for (int i = 0; i < 2; ++i) {
      const int c = w * 2 + i;
      gl_lds16(A + (mbase + c * 16 + srow) * (long)K + kt + scol, &As[c * 512]);
      gl_lds16(B + (nbase + c * 16 + srow) * (long)K + kt + scol, &Bs[c * 512]);
    }
  };

  stage(0, 0);
  __syncthreads();

  const int NTK = K / 32;
  for (int t = 0; t < NTK; ++t) {
    const int cur = t & 1;
    if (t + 1 < NTK) stage(cur ^ 1, (t + 1) * 32);
    __builtin_amdgcn_sched_barrier(0);
    const __bf16* As = (const __bf16*)(smem + cur * 16384);
    const __bf16* Bs = As + 128 * 32;
    bf16x8 af[4], bfv[4];
#pragma unroll
    for (int mm = 0; mm < 4; ++mm)
      af[mm] = *(const bf16x8*)&As[(wr * 64 + mm * 16 + lr) * 32 + lg * 8];
#pragma unroll
    for (int nn = 0; nn < 4; ++nn)
      bfv[nn] = *(const bf16x8*)&Bs[(wc * 64 + nn * 16 + lr) * 32 + lg * 8];
    __builtin_amdgcn_s_setprio(1);
#pragma unroll
    for (int nn = 0; nn < 4; ++nn)
#pragma unroll
      for (int mm = 0; mm < 4; ++mm)
        acc[mm][nn] = __builtin_amdgcn_mfma_f32_16x16x32_bf16(
            af[mm], bfv[nn], acc[mm][nn], 0, 0, 0);
    __builtin_amdgcn_s_setprio(0);
    __syncthreads();
  }

#pragma unroll
  for (int mm = 0; mm < 4; ++mm)
#pragma unroll
    for (int nn = 0; nn < 4; ++nn) {
      const long n = nbase + wc * 64 + nn * 16 + lr;
#pragma unroll
      for (int r = 0; r < 4; ++r) {
        const long m = mbase + wr * 64 + mm * 16 + lg * 4 + r;
        C[m * (long)N + n] = acc[mm][nn][r];
      }
    }
}

// ---------------- fused flash attention v6 (unchanged from R6) ----------------
// QBLK=128, KVBLK=64, 8 waves (512 threads); wave owns 16 q-rows.
// SWAPPED QK^T: sacc = mfma(kf, qf) so each lane holds S[q=lr][k=16 vals]
// lane-locally -> softmax is 2 shfl_xor instead of 16-lane chains (T12 idea).
__global__ __launch_bounds__(512, 4) void attn_fused(
    const __bf16* __restrict__ Q, const __bf16* __restrict__ K,
    const __bf16* __restrict__ Vt, const float* __restrict__ mask,
    __bf16* __restrict__ Out) {
  __shared__ __bf16 Ks[2 * 64 * 128];   // [buf][krow][d], swizzled chunks
  __shared__ __bf16 Vs[2 * 128 * 64];   // [buf][d][kcol], swizzled chunks
  __shared__ __bf16 Ps[128 * 64];       // [qrow][k], byte = 2k ^ ((q&7)<<4)

  const int tid  = threadIdx.x;
  const int lane = tid & 63;
  const int w    = tid >> 6;            // 0..7
  const int lg   = lane >> 4, lr = lane & 15;
  const int flat = blockIdx.y * 16 + blockIdx.x;
  const int swz  = (flat & 7) * 64 + (flat >> 3);
  const int bh   = swz >> 4;
  const int b    = bh >> 4, h = bh & 15;
  const int q0   = (swz & 15) * 128;

  const __bf16* Qh = Q  + (size_t)bh * SEQ * HDSZ;
  const __bf16* Kh = K  + (size_t)bh * SEQ * HDSZ;
  const __bf16* Vh = Vt + (size_t)bh * HDSZ * SEQ;  // [d][s]
  const float*  Mb = mask + (size_t)b * SEQ * SEQ;

  // Q fragments (B-operand now: col=lr -> q-row, k=lg*8+i -> d)
  bf16x8 qf[4];
#pragma unroll
  for (int kk = 0; kk < 4; ++kk)
    qf[kk] = *(const bf16x8*)(
        Qh + (size_t)(q0 + w * 16 + lr) * HDSZ + kk * 32 + lg * 8);

  // staging sources (pre-swizzled global addr, linear LDS dest)
  const __bf16* ksrc[2];
  const __bf16* vsrc[2];
#pragma unroll
  for (int i = 0; i < 2; ++i) {
    const int ch = i * 512 + tid;
    const int krow = ch >> 4, kc = ch & 15;
    ksrc[i] = Kh + (size_t)krow * HDSZ + (((kc & 8) | ((kc ^ krow) & 7)) * 8);
    const int vrow = ch >> 3, vc = ch & 7;
    vsrc[i] = Vh + (size_t)vrow * SEQ + (((vc ^ vrow) & 7) * 8);
  }

  float mrw = -1e30f, lrw = 0.f;     // scalar per lane (q = lr)
  f32x4 acco[8];
#pragma unroll
  for (int n = 0; n < 8; ++n) acco[n] = (f32x4){0.f, 0.f, 0.f, 0.f};

  // prologue: stage tile 0 into buffer 0
#pragma unroll
  for (int i = 0; i < 2; ++i) {
    gl_lds16(ksrc[i], &Ks[(i * 512 + w * 64) * 8]);
    gl_lds16(vsrc[i], &Vs[(i * 512 + w * 64) * 8]);
  }
  __syncthreads();

  constexpr int NT = SEQ / 64;
  for (int t = 0; t < NT; ++t) {
    const int cur = t & 1;
    const int kt = t * 64;
    const char* Kb = (const char*)(Ks + cur * (64 * 128));
    const char* Vb = (const char*)(Vs + cur * (128 * 64));

    // --- (A) mask prefetch (float4, k = n*16 + lg*4 + 0..3) ---
    f32x4 mk[4];
#pragma unroll
    for (int n = 0; n < 4; ++n)
      mk[n] = *(const f32x4*)(
          Mb + (size_t)(q0 + w * 16 + lr) * SEQ + kt + n * 16 + lg * 4);
    __builtin_amdgcn_sched_barrier(0);

    // --- (B) STAGE tile t+1 into buf^1 (drained at end barrier) ---
    if (t + 1 < NT) {
      const int nk = kt + 64;
      __bf16* Kn = Ks + (cur ^ 1) * (64 * 128);
      __bf16* Vn = Vs + (cur ^ 1) * (128 * 64);
#pragma unroll
      for (int i = 0; i < 2; ++i) {
        gl_lds16(ksrc[i] + (size_t)nk * HDSZ, &Kn[(i * 512 + w * 64) * 8]);
        gl_lds16(vsrc[i] + nk, &Vn[(i * 512 + w * 64) * 8]);
      }
    }
    __builtin_amdgcn_sched_barrier(0);

    // --- (C) S = K Q^T (SWAPPED: lane gets q=lr, k=n*16+lg*4+r) ---
    f32x4 sacc[4];
#pragma unroll
    for (int n = 0; n < 4; ++n) sacc[n] = (f32x4){0.f, 0.f, 0.f, 0.f};
    __builtin_amdgcn_s_setprio(1);
#pragma unroll
    for (int n = 0; n < 4; ++n)
#pragma unroll
      for (int kk = 0; kk < 4; ++kk) {
        const int cp = (kk * 4 + lg) ^ (lr & 7);  // swizzled 16B chunk
        bf16x8 kf = *(const bf16x8*)(Kb + ((n * 16 + lr) << 8) + (cp << 4));
        sacc[n] = __builtin_amdgcn_mfma_f32_16x16x32_bf16(kf, qf[kk], sacc[n], 0, 0, 0);
      }
    __builtin_amdgcn_s_setprio(0);

    // --- (D) lane-local online softmax (row q = lr, 16 k per lane) ---
    float sv[4][4];
    float tm = -1e30f;
#pragma unroll
    for (int n = 0; n < 4; ++n)
#pragma unroll
      for (int r = 0; r < 4; ++r) {
        float x = fmaf(sacc[n][r], QK_SCALE, mk[n][r]);
        sv[n][r] = x;
        tm = fmaxf(tm, x);
      }
    tm = fmaxf(tm, __shfl_xor(tm, 16));
    tm = fmaxf(tm, __shfl_xor(tm, 32));
    const float mn = fmaxf(mrw, tm);
    const float corr = __expf(mrw - mn);
    mrw = mn;
    float ls = 0.f;
#pragma unroll
    for (int n = 0; n < 4; ++n)
#pragma unroll
      for (int r = 0; r < 4; ++r) {
        float p = __expf(sv[n][r] - mn);
        sv[n][r] = p;
        ls += p;
      }
    ls += __shfl_xor(ls, 16);
    ls += __shfl_xor(ls, 32);
    lrw = lrw * corr + ls;
    // corr broadcast into PV accumulator layout (rows q = lg*4 + r)
    float cb[4];
#pragma unroll
    for (int r = 0; r < 4; ++r) cb[r] = __shfl(corr, lg * 4 + r);
#pragma unroll
    for (int n = 0; n < 8; ++n)
#pragma unroll
      for (int r = 0; r < 4; ++r) acco[n][r] *= cb[r];

    // --- (E) P -> LDS, packed b32 (k pairs are r-adjacent now) ---
#pragma unroll
    for (int n = 0; n < 4; ++n)
#pragma unroll
      for (int rp = 0; rp < 2; ++rp) {
        bf16x2 pk = { (__bf16)sv[n][2 * rp], (__bf16)sv[n][2 * rp + 1] };
        const int pbyte = (n * 32 + lg * 8 + rp * 4) ^ ((lr & 7) << 4);
        *(bf16x2*)((char*)Ps + (w * 16 + lr) * 128 + pbyte) = pk;
      }
    __asm__ volatile("s_waitcnt lgkmcnt(0)" ::: "memory");
    __builtin_amdgcn_sched_barrier(0);

    // --- (F) O += P V ---
    __builtin_amdgcn_s_setprio(1);
#pragma unroll
    for (int kk = 0; kk < 2; ++kk) {
      const int pcp = (kk * 4 + lg) ^ (lr & 7);
      bf16x8 pa = *(const bf16x8*)(
          (const char*)Ps + (w * 16 + lr) * 128 + (pcp << 4));
#pragma unroll
      for (int n = 0; n < 8; ++n) {
        const int cp = (kk * 4 + lg) ^ (lr & 7);
        bf16x8 vf = *(const bf16x8*)(Vb + ((n * 16 + lr) << 7) + (cp << 4));
        acco[n] = __builtin_amdgcn_mfma_f32_16x16x32_bf16(pa, vf, acco[n], 0, 0, 0);
      }
    }
    __builtin_amdgcn_s_setprio(0);

    // --- (G) publish next buffer / protect current ---
    __syncthreads();
  }

  // --- epilogue: normalize, write attn out as [b, s, h*128+d] bf16 ---
  float lb[4];
#pragma unroll
  for (int r = 0; r < 4; ++r) lb[r] = __shfl(lrw, lg * 4 + r);
#pragma unroll
  for (int r = 0; r < 4; ++r) {
    const float inv = 1.0f / lb[r];
    const int srow = q0 + w * 16 + lg * 4 + r;
    const size_t base = ((size_t)b * SEQ + srow) * HDIM + h * HDSZ;
#pragma unroll
    for (int n = 0; n < 8; ++n)
      Out[base + n * 16 + lr] = (__bf16)(acco[n][r] * inv);
  }
}

// ---------------- launcher ----------------
extern "C" void kernel_launch(void* const* d_in, const int* in_sizes, int n_in,
                              void* d_out, int out_size, void* d_ws, size_t ws_size,
                              hipStream_t stream) {
  const float* x    = (const float*)d_in[0];
  const float* mask = (const float*)d_in[1];
  const float* wq   = (const float*)d_in[2];
  const float* wk   = (const float*)d_in[3];
  const float* wv   = (const float*)d_in[4];
  const float* wo   = (const float*)d_in[5];

  constexpr long XN = 4096L * 2048;  // 8388608
  constexpr long WN = 2048L * 2048;  // 4194304

  __bf16* xbf = (__bf16*)d_ws;
  __bf16* wqb = xbf + XN;            // wq;wk;wv;wo contiguous (cast4)
  __bf16* wob = wqb + 3 * WN;
  __bf16* qw  = wqb + 4 * WN;        // Q [b,h,s,d]
  __bf16* kw  = qw + XN;             // K [b,h,s,d]
  __bf16* vtw = kw + XN;             // V^T [b,h,d,s]
  __bf16* aw  = vtw + XN;            // attention output [4096][2048]

  cast_f32_bf16<<<2048, 256, 0, stream>>>(x, xbf, (int)(XN / 4));
  cast4_f32_bf16<<<dim3(256, 4), 256, 0, stream>>>(wq, wk, wv, wo, wqb,
                                                   (int)(WN / 4));

  gemm_qkv<<<dim3(48, 32), 256, 0, stream>>>(xbf, wqb, qw);

  attn_fused<<<dim3(16, 32), 512, 0, stream>>>(qw, kw, vtw, mask, aw);

  gemm_bt_f32<<<dim3(16, 32), 256, 0, stream>>>(aw, wob, (float*)d_out,
                                                4096, 2048, 2048);
}